// Round 1
// 1144.918 us; speedup vs baseline: 1.0941x; 1.0941x over previous
//
#include <hip/hip_runtime.h>
#include <hip/hip_bf16.h>

// Problem constants (GeoUmpForPretrain) — all tensors fp32 per reference.
constexpr int B = 16, S = 512, H = 768, T = 2, N = 32, L = 64, E = 8, D = 128, A = 128;
constexpr float INV_SQRT_D = 0.08838834764831843f;  // 1/sqrt(128)

// ---------------------------------------------------------------------------
// Tiled fp32 GEMM core: C[r0:r0+128, c0:c0+128] = A @ W (+ bias)
// A: [M,K] row-major (lda); W: [K,N] row-major (ldw); C row-major (ldc).
// 256 threads, 8x8 outputs/thread, BK=32. K must be a multiple of 32.
// bias may be nullptr. One call site per kernel (one LDS allocation).
__device__ __forceinline__ void gemm128(const float* __restrict__ Ap, int lda,
                                        const float* __restrict__ W, int ldw,
                                        const float* __restrict__ bias,
                                        float* __restrict__ C, int ldc,
                                        int r0, int c0, int K) {
    __shared__ float As[32][132];   // [kk][row], row-stride 132 (16B-aligned rows)
    __shared__ float Ws[32][128];   // [kk][col]
    const int tid = threadIdx.x;
    const int tr = (tid >> 4) << 3;          // 0,8,...,120
    const int tc = (tid & 15) << 3;          // 0,8,...,120
    float acc[8][8];
    #pragma unroll
    for (int i = 0; i < 8; i++)
        #pragma unroll
        for (int j = 0; j < 8; j++) acc[i][j] = 0.f;

    const int ar = tid >> 3;                 // 0..31  (A tile row base)
    const int ak = (tid & 7) << 2;           // 0..28  (A tile col, float4)
    const int wr = tid >> 5;                 // 0..7   (W tile row base)
    const int wc = (tid & 31) << 2;          // 0..124 (W tile col, float4)

    for (int k0 = 0; k0 < K; k0 += 32) {
        float4 av[4], wv[4];
        #pragma unroll
        for (int p = 0; p < 4; p++) {
            av[p] = *(const float4*)&Ap[(size_t)(r0 + ar + 32 * p) * lda + k0 + ak];
            wv[p] = *(const float4*)&W[(size_t)(k0 + wr + 8 * p) * ldw + c0 + wc];
        }
        __syncthreads();   // previous tile's LDS reads done
        #pragma unroll
        for (int p = 0; p < 4; p++) {
            As[ak + 0][ar + 32 * p] = av[p].x;
            As[ak + 1][ar + 32 * p] = av[p].y;
            As[ak + 2][ar + 32 * p] = av[p].z;
            As[ak + 3][ar + 32 * p] = av[p].w;
            *(float4*)&Ws[wr + 8 * p][wc] = wv[p];
        }
        __syncthreads();
        #pragma unroll
        for (int kk = 0; kk < 32; kk++) {
            float a[8], b[8];
            *(float4*)&a[0] = *(const float4*)&As[kk][tr];
            *(float4*)&a[4] = *(const float4*)&As[kk][tr + 4];
            *(float4*)&b[0] = *(const float4*)&Ws[kk][tc];
            *(float4*)&b[4] = *(const float4*)&Ws[kk][tc + 4];
            #pragma unroll
            for (int i = 0; i < 8; i++)
                #pragma unroll
                for (int j = 0; j < 8; j++) acc[i][j] += a[i] * b[j];
        }
    }
    #pragma unroll
    for (int i = 0; i < 8; i++) {
        float o[8];
        #pragma unroll
        for (int j = 0; j < 8; j++)
            o[j] = acc[i][j] + (bias ? bias[c0 + tc + j] : 0.f);
        *(float4*)&C[(size_t)(r0 + tr + i) * ldc + c0 + tc] = *(float4*)&o[0];
        *(float4*)&C[(size_t)(r0 + tr + i) * ldc + c0 + tc + 4] = *(float4*)&o[4];
    }
}

// K3: kbuf = neigh_emb @ Wk + bk   [65536, 128]
__global__ void k_kproj(const float* __restrict__ neigh, const float* __restrict__ Wk,
                        const float* __restrict__ bk, float* __restrict__ kbuf) {
    gemm128(neigh, H, Wk, D, bk, kbuf, D, blockIdx.x * 128, 0, H);
}

// K8a: q2 = x@Wq+bq (y=0), k2 = x@Wk+bk (y=1).  grid (64, 2)
__global__ void k_qk2(const float* __restrict__ x,
                      const float* __restrict__ Wq, const float* __restrict__ bq,
                      const float* __restrict__ Wk, const float* __restrict__ bk,
                      float* __restrict__ q2, float* __restrict__ k2) {
    const float* W = blockIdx.y ? Wk : Wq;
    const float* bs = blockIdx.y ? bk : bq;
    float* C = blockIdx.y ? k2 : q2;
    gemm128(x, H, W, D, bs, C, D, blockIdx.x * 128, 0, H);
}

// K9c: out[b] = P[b] @ v2[b].  grid (4, 6, 16)
__global__ void k_pv(const float* __restrict__ P, const float* __restrict__ v2,
                     float* __restrict__ out) {
    int b = blockIdx.z;
    gemm128(P + (size_t)b * S * S, S, v2 + (size_t)b * S * H, H, nullptr,
            out + (size_t)b * S * H, H, blockIdx.x * 128, blockIdx.y * 128, S);
}

// ---------------------------------------------------------------------------
// K9a: Smat[b] = q2[b] @ k2[b]^T * INV_SQRT_D.  grid (4, 4, 16).
// Both operands staged K-major in LDS (B is transposed by staging).
__global__ void k_qkT(const float* __restrict__ q2, const float* __restrict__ k2,
                      float* __restrict__ Smat) {
    __shared__ float Qs[32][132];
    __shared__ float Ks[32][132];
    const int b = blockIdx.z;
    const int r0 = blockIdx.x * 128, c0 = blockIdx.y * 128;
    const float* Qb = q2 + (size_t)b * S * D;
    const float* Kb = k2 + (size_t)b * S * D;
    float* Sb = Smat + (size_t)b * S * S;
    const int tid = threadIdx.x;
    const int tr = (tid >> 4) << 3;
    const int tc = (tid & 15) << 3;
    const int ar = tid >> 3;             // 0..31
    const int ak = (tid & 7) << 2;       // 0..28
    float acc[8][8];
    #pragma unroll
    for (int i = 0; i < 8; i++)
        #pragma unroll
        for (int j = 0; j < 8; j++) acc[i][j] = 0.f;

    for (int k0 = 0; k0 < D; k0 += 32) {
        float4 qv[4], kv[4];
        #pragma unroll
        for (int p = 0; p < 4; p++) {
            qv[p] = *(const float4*)&Qb[(size_t)(r0 + ar + 32 * p) * D + k0 + ak];
            kv[p] = *(const float4*)&Kb[(size_t)(c0 + ar + 32 * p) * D + k0 + ak];
        }
        __syncthreads();
        #pragma unroll
        for (int p = 0; p < 4; p++) {
            Qs[ak + 0][ar + 32 * p] = qv[p].x;
            Qs[ak + 1][ar + 32 * p] = qv[p].y;
            Qs[ak + 2][ar + 32 * p] = qv[p].z;
            Qs[ak + 3][ar + 32 * p] = qv[p].w;
            Ks[ak + 0][ar + 32 * p] = kv[p].x;
            Ks[ak + 1][ar + 32 * p] = kv[p].y;
            Ks[ak + 2][ar + 32 * p] = kv[p].z;
            Ks[ak + 3][ar + 32 * p] = kv[p].w;
        }
        __syncthreads();
        #pragma unroll
        for (int kk = 0; kk < 32; kk++) {
            float a[8], bb_[8];
            *(float4*)&a[0] = *(const float4*)&Qs[kk][tr];
            *(float4*)&a[4] = *(const float4*)&Qs[kk][tr + 4];
            *(float4*)&bb_[0] = *(const float4*)&Ks[kk][tc];
            *(float4*)&bb_[4] = *(const float4*)&Ks[kk][tc + 4];
            #pragma unroll
            for (int i = 0; i < 8; i++)
                #pragma unroll
                for (int j = 0; j < 8; j++) acc[i][j] += a[i] * bb_[j];
        }
    }
    #pragma unroll
    for (int i = 0; i < 8; i++) {
        float o[8];
        #pragma unroll
        for (int j = 0; j < 8; j++) o[j] = acc[i][j] * INV_SQRT_D;
        *(float4*)&Sb[(size_t)(r0 + tr + i) * S + c0 + tc] = *(float4*)&o[0];
        *(float4*)&Sb[(size_t)(r0 + tr + i) * S + c0 + tc + 4] = *(float4*)&o[4];
    }
}

// K9b: in-place row softmax on Smat. One wave per row; 4 rows/block.
__global__ void k_smax(float* __restrict__ Smat) {
    int row = blockIdx.x * 4 + (threadIdx.x >> 6);
    int lane = threadIdx.x & 63;
    float* p = Smat + (size_t)row * S;
    float4 v0 = *(const float4*)&p[lane * 4];
    float4 v1 = *(const float4*)&p[256 + lane * 4];
    float m = fmaxf(fmaxf(fmaxf(v0.x, v0.y), fmaxf(v0.z, v0.w)),
                    fmaxf(fmaxf(v1.x, v1.y), fmaxf(v1.z, v1.w)));
    #pragma unroll
    for (int off = 32; off; off >>= 1) m = fmaxf(m, __shfl_xor(m, off, 64));
    v0.x = expf(v0.x - m); v0.y = expf(v0.y - m);
    v0.z = expf(v0.z - m); v0.w = expf(v0.w - m);
    v1.x = expf(v1.x - m); v1.y = expf(v1.y - m);
    v1.z = expf(v1.z - m); v1.w = expf(v1.w - m);
    float s = v0.x + v0.y + v0.z + v0.w + v1.x + v1.y + v1.z + v1.w;
    #pragma unroll
    for (int off = 32; off; off >>= 1) s += __shfl_xor(s, off, 64);
    float inv = 1.0f / s;
    v0.x *= inv; v0.y *= inv; v0.z *= inv; v0.w *= inv;
    v1.x *= inv; v1.y *= inv; v1.z *= inv; v1.w *= inv;
    *(float4*)&p[lane * 4] = v0;
    *(float4*)&p[256 + lane * 4] = v1;
}

// ---------------------------------------------------------------------------
// K1: gather entity spans -> e_fea [B,T,E,H], feas = mean over E [B,T,H]
__global__ void k_gather(const float* __restrict__ xs,
                         const int* __restrict__ spans,
                         float* __restrict__ e_fea, float* __restrict__ feas) {
    int bt = blockIdx.x;
    int b = bt / T;
    int span = spans[bt];
    for (int h = threadIdx.x; h < H; h += 256) {
        float acc = 0.f;
        for (int e = 0; e < E; e++) {
            float v = xs[((size_t)b * S + span + e) * H + h];
            e_fea[((size_t)bt * E + e) * H + h] = v;
            acc += v;
        }
        feas[(size_t)bt * H + h] = acc * (1.0f / E);
    }
}

// ---------------------------------------------------------------------------
// K2: q = e_fea @ Wq + bq   [B*T*E, D]  (tiny: 256 rows)
__global__ void k_qproj(const float* __restrict__ e_fea,
                        const float* __restrict__ Wq,
                        const float* __restrict__ bq,
                        float* __restrict__ q) {
    int row = blockIdx.x;
    int d = threadIdx.x;
    const float* er = e_fea + (size_t)row * H;
    float acc = bq[d];
    #pragma unroll 4
    for (int h = 0; h < H; h++) acc += er[h] * Wq[(size_t)h * D + d];
    q[(size_t)row * D + d] = acc;
}

// ---------------------------------------------------------------------------
// K4: per (b,t,n): logits = q k^T / sqrt(D); softmax over L; store probs
//     attn_p [btn,E,L]; pooled[btn,h] = (mean_e attn) @ neigh.
__global__ void k_sdpa(const float* __restrict__ q, const float* __restrict__ kbuf,
                       const float* __restrict__ neigh,
                       float* __restrict__ attn_p, float* __restrict__ pooled) {
    __shared__ float q_s[E * D];
    __shared__ float k_s[L * 129];
    __shared__ float attn_s[E * L];
    __shared__ float abar_s[L];
    int btn = blockIdx.x;
    int bt = btn / N;
    const float* qrow = q + (size_t)bt * E * D;
    const float* krow = kbuf + (size_t)btn * L * D;
    const float* nrow = neigh + (size_t)btn * L * H;

    for (int i = threadIdx.x; i < E * D; i += 256) q_s[i] = qrow[i];
    for (int i = threadIdx.x; i < L * D; i += 256) {
        int l = i >> 7, d = i & 127;
        k_s[l * 129 + d] = krow[i];
    }
    __syncthreads();

    for (int p = threadIdx.x; p < E * L; p += 256) {
        int e = p >> 6, l = p & 63;
        float acc = 0.f;
        #pragma unroll 4
        for (int d = 0; d < D; d++) acc += q_s[e * D + d] * k_s[l * 129 + d];
        attn_s[e * L + l] = acc * INV_SQRT_D;
    }
    __syncthreads();

    if (threadIdx.x < E) {
        int e = threadIdx.x;
        float m = -1e30f;
        for (int l = 0; l < L; l++) m = fmaxf(m, attn_s[e * L + l]);
        float ssum = 0.f;
        for (int l = 0; l < L; l++) {
            float ex = expf(attn_s[e * L + l] - m);
            attn_s[e * L + l] = ex;
            ssum += ex;
        }
        float inv = 1.0f / ssum;
        for (int l = 0; l < L; l++) attn_s[e * L + l] *= inv;
    }
    __syncthreads();

    for (int i = threadIdx.x; i < E * L; i += 256)
        attn_p[(size_t)btn * E * L + i] = attn_s[i];
    if (threadIdx.x < L) {
        float s = 0.f;
        #pragma unroll
        for (int e = 0; e < E; e++) s += attn_s[e * L + threadIdx.x];
        abar_s[threadIdx.x] = s * (1.0f / E);
    }
    __syncthreads();

    for (int h = threadIdx.x; h < H; h += 256) {
        float acc = 0.f;
        for (int l = 0; l < L; l++) acc += abar_s[l] * nrow[(size_t)l * H + h];
        pooled[(size_t)btn * H + h] = acc;
    }
}

// ---------------------------------------------------------------------------
// K5a: fold Ww/Wa/bw/ba/wb/bb into misc
__global__ void k_uv(const float* __restrict__ Ww, const float* __restrict__ bw,
                     const float* __restrict__ Wa, const float* __restrict__ ba,
                     const float* __restrict__ wb, const float* __restrict__ bb,
                     float* __restrict__ misc) {
    int h = blockIdx.x * blockDim.x + threadIdx.x;
    if (h < H) {
        float lo = 0.f, hi = 0.f;
        for (int a = 0; a < A; a++) {
            float w = Ww[(size_t)h * A + a];
            lo += w * Wa[a];
            hi += w * Wa[A + a];
        }
        misc[h] = lo;
        misc[H + h] = hi;
    }
    if (blockIdx.x == 0 && threadIdx.x == 0) {
        float c = ba[0];
        for (int a = 0; a < A; a++) c += bw[a] * (Wa[a] + Wa[A + a]);
        misc[2 * H] = c;
        misc[2 * H + 1] = wb[0];
        misc[2 * H + 2] = bb[0];
    }
}

// ---------------------------------------------------------------------------
// K5b: score[btn] = sigmoid(leaky(feas@v + pooled@u + c0) + dist*wb + bb)
__global__ void k_score(const float* __restrict__ feas, const float* __restrict__ pooled,
                        const float* __restrict__ misc, const float* __restrict__ dists,
                        float* __restrict__ score) {
    __shared__ float red[4];
    int btn = blockIdx.x;
    int bt = btn / N;
    float part = 0.f;
    for (int h = threadIdx.x; h < H; h += 256)
        part += feas[(size_t)bt * H + h] * misc[h] + pooled[(size_t)btn * H + h] * misc[H + h];
    #pragma unroll
    for (int off = 32; off > 0; off >>= 1) part += __shfl_down(part, off, 64);
    if ((threadIdx.x & 63) == 0) red[threadIdx.x >> 6] = part;
    __syncthreads();
    if (threadIdx.x == 0) {
        float tot = red[0] + red[1] + red[2] + red[3] + misc[2 * H];
        float lk = tot > 0.f ? tot : 0.01f * tot;
        float xatt = lk + dists[btn] * misc[2 * H + 1] + misc[2 * H + 2];
        score[btn] = 1.0f / (1.0f + expf(-xatt));
    }
}

// ---------------------------------------------------------------------------
// K6: delta[bt,e,h] += sum_{n, l-chunk} score_n * attn_p[n,e,l] * neigh[l,h]
__global__ void k_delta(const float* __restrict__ attn_p, const float* __restrict__ score,
                        const float* __restrict__ neigh, float* __restrict__ delta) {
    __shared__ float w_s[E * 8];
    int bt = blockIdx.x, l0 = blockIdx.y * 8;
    float acc[E][3];
    #pragma unroll
    for (int e = 0; e < E; e++)
        #pragma unroll
        for (int c = 0; c < 3; c++) acc[e][c] = 0.f;
    for (int n = 0; n < N; n++) {
        int btn = bt * N + n;
        if (threadIdx.x < E * 8) {
            int e = threadIdx.x >> 3, lp = threadIdx.x & 7;
            w_s[threadIdx.x] = score[btn] * attn_p[((size_t)btn * E + e) * L + l0 + lp];
        }
        __syncthreads();
        const float* nrow = neigh + ((size_t)btn * L + l0) * H;
        for (int lp = 0; lp < 8; lp++) {
            float nv[3];
            #pragma unroll
            for (int c = 0; c < 3; c++) nv[c] = nrow[(size_t)lp * H + threadIdx.x + c * 256];
            #pragma unroll
            for (int e = 0; e < E; e++) {
                float w = w_s[e * 8 + lp];
                #pragma unroll
                for (int c = 0; c < 3; c++) acc[e][c] += w * nv[c];
            }
        }
        __syncthreads();
    }
    #pragma unroll
    for (int e = 0; e < E; e++)
        #pragma unroll
        for (int c = 0; c < 3; c++)
            atomicAdd(&delta[((size_t)bt * E + e) * H + threadIdx.x + c * 256], acc[e][c]);
}

// ---------------------------------------------------------------------------
// K7: x[b, span+e, h] += delta[bt,e,h]  (atomic: T spans may overlap)
__global__ void k_addspan(const float* __restrict__ delta, const int* __restrict__ spans,
                          float* __restrict__ x) {
    int i = blockIdx.x * 256 + threadIdx.x;
    int h = i % H;
    int e = (i / H) % E;
    int bt = i / (H * E);
    int b = bt / T;
    atomicAdd(&x[((size_t)b * S + spans[bt] + e) * H + h], delta[i]);
}

// ---------------------------------------------------------------------------
// K8b: v2 = x@Wv+bv IN-PLACE over x. Block owns 16 rows exclusively: stages
// them transposed in LDS ([h][r], stride 20 -> 16B-aligned rows), then
// overwrites. In-place safe (each block reads only rows it staged).
//
// R1 rewrite: 768 threads (12 waves) share the one 61.4KB LDS stage so the
// 2-blocks/CU LDS limit now yields 24 waves/CU (was 8 -> Occupancy 23%,
// VALUBusy 32%, 295 us). Thread t owns output column t (acc[16], 1 Wv
// load/h vs old 3); 8-deep Wv prefetch covers L2 latency; x-row values are
// same-address LDS broadcasts (conflict-free). __launch_bounds__(768,8)
// pins VGPR<=64: at >64 VGPR the occupancy step would drop us to a single
// 12-wave block/CU.
__global__ __launch_bounds__(768, 8) void k_v2(float* __restrict__ xv,
                                               const float* __restrict__ Wv,
                                               const float* __restrict__ bv) {
    __shared__ float x_s[H * 20];   // 61,440 B: [h][r], row-stride 20
    const int r0 = blockIdx.x * 16;
    const int t = threadIdx.x;      // 0..767 = h-index for staging, out col
    #pragma unroll
    for (int j = 0; j < 16; j++)
        x_s[t * 20 + j] = xv[(size_t)(r0 + j) * H + t];
    __syncthreads();

    float acc[16];
    #pragma unroll
    for (int r = 0; r < 16; r++) acc[r] = 0.f;

    const float* wp = Wv + t;
    for (int h = 0; h < H; h += 8) {
        float w[8];
        #pragma unroll
        for (int u = 0; u < 8; u++) w[u] = wp[(size_t)(h + u) * H];
        #pragma unroll
        for (int u = 0; u < 8; u++) {
            float4 a0 = *(const float4*)&x_s[(h + u) * 20 + 0];
            float4 a1 = *(const float4*)&x_s[(h + u) * 20 + 4];
            float4 a2 = *(const float4*)&x_s[(h + u) * 20 + 8];
            float4 a3 = *(const float4*)&x_s[(h + u) * 20 + 12];
            acc[0]  += a0.x * w[u]; acc[1]  += a0.y * w[u];
            acc[2]  += a0.z * w[u]; acc[3]  += a0.w * w[u];
            acc[4]  += a1.x * w[u]; acc[5]  += a1.y * w[u];
            acc[6]  += a1.z * w[u]; acc[7]  += a1.w * w[u];
            acc[8]  += a2.x * w[u]; acc[9]  += a2.y * w[u];
            acc[10] += a2.z * w[u]; acc[11] += a2.w * w[u];
            acc[12] += a3.x * w[u]; acc[13] += a3.y * w[u];
            acc[14] += a3.z * w[u]; acc[15] += a3.w * w[u];
        }
    }
    const float bias = bv[t];
    #pragma unroll
    for (int r = 0; r < 16; r++)
        xv[(size_t)(r0 + r) * H + t] = acc[r] + bias;
}

// ---------------------------------------------------------------------------
extern "C" void kernel_launch(void* const* d_in, const int* in_sizes, int n_in,
                              void* d_out, int out_size, void* d_ws, size_t ws_size,
                              hipStream_t stream) {
    const float* xs    = (const float*)d_in[0];
    const float* neigh = (const float*)d_in[1];
    const float* dists = (const float*)d_in[2];
    const int*   spans = (const int*)d_in[3];
    const float* Wq = (const float*)d_in[4];
    const float* bq = (const float*)d_in[5];
    const float* Wk = (const float*)d_in[6];
    const float* bk = (const float*)d_in[7];
    const float* Wv = (const float*)d_in[8];
    const float* bv = (const float*)d_in[9];
    const float* Ww = (const float*)d_in[10];
    const float* bw = (const float*)d_in[11];
    const float* Wa = (const float*)d_in[12];
    const float* ba = (const float*)d_in[13];
    const float* wb = (const float*)d_in[14];
    const float* bb = (const float*)d_in[15];
    float* out = (float*)d_out;

    // Workspace layout (fp32), total 12,582,912 floats = 48 MiB.
    // Region A [0, 8388608): kbuf [65536,128] (dead after k_sdpa) -> reused
    //   exactly as x (6291456) | q2 (1048576) | k2 (1048576); v2 in-place on x.
    // Region B [8388608, 12582912): early-phase smalls (attn_p..scoreb,
    //   1764352 floats, all dead before k_qkT) -> then Smat [B,S,S] (4194304).
    float* ws     = (float*)d_ws;
    float* kb     = ws;                                   // 8,388,608
    float* regB   = ws + (size_t)8388608;
    float* attn_p = regB;                                 //   524,288
    float* pooled = attn_p + (size_t)B * T * N * E * L;   //   786,432
    float* delta  = pooled + (size_t)B * T * N * H;       //   196,608
    float* e_fea  = delta + (size_t)B * T * E * H;        //   196,608
    float* qb     = e_fea + (size_t)B * T * E * H;        //    32,768
    float* feas   = qb + (size_t)B * T * E * D;           //    24,576
    float* misc   = feas + (size_t)B * T * H;             //     2,048
    float* scoreb = misc + 2048;                          //     1,024
    float* x      = kb;                                   // alias (kb dead)
    float* q2     = kb + (size_t)B * S * H;               // alias
    float* k2     = q2 + (size_t)B * S * D;               // alias
    float* v2     = x;                                    // in-place
    float* Smat   = regB;                                 // alias (smalls dead)

    k_gather<<<B * T, 256, 0, stream>>>(xs, spans, e_fea, feas);
    k_qproj<<<B * T * E, D, 0, stream>>>(e_fea, Wq, bq, qb);
    k_kproj<<<B * T * N * L / 128, 256, 0, stream>>>(neigh, Wk, bk, kb);
    k_sdpa<<<B * T * N, 256, 0, stream>>>(qb, kb, neigh, attn_p, pooled);
    k_uv<<<3, 256, 0, stream>>>(Ww, bw, Wa, ba, wb, bb, misc);
    k_score<<<B * T * N, 256, 0, stream>>>(feas, pooled, misc, dists, scoreb);
    hipMemsetAsync(delta, 0, (size_t)B * T * E * H * sizeof(float), stream);
    k_delta<<<dim3(B * T, L / 8), 256, 0, stream>>>(attn_p, scoreb, neigh, delta);
    hipMemcpyAsync(x, xs, (size_t)B * S * H * sizeof(float), hipMemcpyDeviceToDevice, stream);
    k_addspan<<<(B * T * E * H) / 256, 256, 0, stream>>>(delta, spans, x);
    k_qk2<<<dim3(B * S / 128, 2), 256, 0, stream>>>(x, Wq, bq, Wk, bk, q2, k2);
    k_v2<<<B * S / 16, 768, 0, stream>>>(v2, Wv, bv);
    k_qkT<<<dim3(S / 128, S / 128, B), 256, 0, stream>>>(q2, k2, Smat);
    k_smax<<<B * S / 4, 256, 0, stream>>>(Smat);
    k_pv<<<dim3(S / 128, H / 128, B), 256, 0, stream>>>(Smat, v2, out);
}

// Round 2
// 1042.823 us; speedup vs baseline: 1.2013x; 1.0979x over previous
//
#include <hip/hip_runtime.h>
#include <hip/hip_bf16.h>

// Problem constants (GeoUmpForPretrain) — all tensors fp32 per reference.
constexpr int B = 16, S = 512, H = 768, T = 2, N = 32, L = 64, E = 8, D = 128, A = 128;
constexpr float INV_SQRT_D = 0.08838834764831843f;  // 1/sqrt(128)

// ---------------------------------------------------------------------------
// Tiled fp32 GEMM core: C[r0:r0+128, c0:c0+128] = A @ W (+ bias)
// A: [M,K] row-major (lda); W: [K,N] row-major (ldw); C row-major (ldc).
// 256 threads, 8x8 outputs/thread, BK=32. K must be a multiple of 32.
// bias may be nullptr. One call site per kernel (one LDS allocation).
__device__ __forceinline__ void gemm128(const float* __restrict__ Ap, int lda,
                                        const float* __restrict__ W, int ldw,
                                        const float* __restrict__ bias,
                                        float* __restrict__ C, int ldc,
                                        int r0, int c0, int K) {
    __shared__ float As[32][132];   // [kk][row], row-stride 132 (16B-aligned rows)
    __shared__ float Ws[32][128];   // [kk][col]
    const int tid = threadIdx.x;
    const int tr = (tid >> 4) << 3;          // 0,8,...,120
    const int tc = (tid & 15) << 3;          // 0,8,...,120
    float acc[8][8];
    #pragma unroll
    for (int i = 0; i < 8; i++)
        #pragma unroll
        for (int j = 0; j < 8; j++) acc[i][j] = 0.f;

    const int ar = tid >> 3;                 // 0..31  (A tile row base)
    const int ak = (tid & 7) << 2;           // 0..28  (A tile col, float4)
    const int wr = tid >> 5;                 // 0..7   (W tile row base)
    const int wc = (tid & 31) << 2;          // 0..124 (W tile col, float4)

    for (int k0 = 0; k0 < K; k0 += 32) {
        float4 av[4], wv[4];
        #pragma unroll
        for (int p = 0; p < 4; p++) {
            av[p] = *(const float4*)&Ap[(size_t)(r0 + ar + 32 * p) * lda + k0 + ak];
            wv[p] = *(const float4*)&W[(size_t)(k0 + wr + 8 * p) * ldw + c0 + wc];
        }
        __syncthreads();   // previous tile's LDS reads done
        #pragma unroll
        for (int p = 0; p < 4; p++) {
            As[ak + 0][ar + 32 * p] = av[p].x;
            As[ak + 1][ar + 32 * p] = av[p].y;
            As[ak + 2][ar + 32 * p] = av[p].z;
            As[ak + 3][ar + 32 * p] = av[p].w;
            *(float4*)&Ws[wr + 8 * p][wc] = wv[p];
        }
        __syncthreads();
        #pragma unroll
        for (int kk = 0; kk < 32; kk++) {
            float a[8], b[8];
            *(float4*)&a[0] = *(const float4*)&As[kk][tr];
            *(float4*)&a[4] = *(const float4*)&As[kk][tr + 4];
            *(float4*)&b[0] = *(const float4*)&Ws[kk][tc];
            *(float4*)&b[4] = *(const float4*)&Ws[kk][tc + 4];
            #pragma unroll
            for (int i = 0; i < 8; i++)
                #pragma unroll
                for (int j = 0; j < 8; j++) acc[i][j] += a[i] * b[j];
        }
    }
    #pragma unroll
    for (int i = 0; i < 8; i++) {
        float o[8];
        #pragma unroll
        for (int j = 0; j < 8; j++)
            o[j] = acc[i][j] + (bias ? bias[c0 + tc + j] : 0.f);
        *(float4*)&C[(size_t)(r0 + tr + i) * ldc + c0 + tc] = *(float4*)&o[0];
        *(float4*)&C[(size_t)(r0 + tr + i) * ldc + c0 + tc + 4] = *(float4*)&o[4];
    }
}

// K8a: q2 = x@Wq+bq (y=0), k2 = x@Wk+bk (y=1).  grid (64, 2)
__global__ void k_qk2(const float* __restrict__ x,
                      const float* __restrict__ Wq, const float* __restrict__ bq,
                      const float* __restrict__ Wk, const float* __restrict__ bk,
                      float* __restrict__ q2, float* __restrict__ k2) {
    const float* W = blockIdx.y ? Wk : Wq;
    const float* bs = blockIdx.y ? bk : bq;
    float* C = blockIdx.y ? k2 : q2;
    gemm128(x, H, W, D, bs, C, D, blockIdx.x * 128, 0, H);
}

// K9c: out[b] = P[b] @ v2[b].  grid (4, 6, 16)
__global__ void k_pv(const float* __restrict__ P, const float* __restrict__ v2,
                     float* __restrict__ out) {
    int b = blockIdx.z;
    gemm128(P + (size_t)b * S * S, S, v2 + (size_t)b * S * H, H, nullptr,
            out + (size_t)b * S * H, H, blockIdx.x * 128, blockIdx.y * 128, S);
}

// ---------------------------------------------------------------------------
// K9a: Smat[b] = q2[b] @ k2[b]^T * INV_SQRT_D.  grid (4, 4, 16).
// Both operands staged K-major in LDS (B is transposed by staging).
__global__ void k_qkT(const float* __restrict__ q2, const float* __restrict__ k2,
                      float* __restrict__ Smat) {
    __shared__ float Qs[32][132];
    __shared__ float Ks[32][132];
    const int b = blockIdx.z;
    const int r0 = blockIdx.x * 128, c0 = blockIdx.y * 128;
    const float* Qb = q2 + (size_t)b * S * D;
    const float* Kb = k2 + (size_t)b * S * D;
    float* Sb = Smat + (size_t)b * S * S;
    const int tid = threadIdx.x;
    const int tr = (tid >> 4) << 3;
    const int tc = (tid & 15) << 3;
    const int ar = tid >> 3;             // 0..31
    const int ak = (tid & 7) << 2;       // 0..28
    float acc[8][8];
    #pragma unroll
    for (int i = 0; i < 8; i++)
        #pragma unroll
        for (int j = 0; j < 8; j++) acc[i][j] = 0.f;

    for (int k0 = 0; k0 < D; k0 += 32) {
        float4 qv[4], kv[4];
        #pragma unroll
        for (int p = 0; p < 4; p++) {
            qv[p] = *(const float4*)&Qb[(size_t)(r0 + ar + 32 * p) * D + k0 + ak];
            kv[p] = *(const float4*)&Kb[(size_t)(c0 + ar + 32 * p) * D + k0 + ak];
        }
        __syncthreads();
        #pragma unroll
        for (int p = 0; p < 4; p++) {
            Qs[ak + 0][ar + 32 * p] = qv[p].x;
            Qs[ak + 1][ar + 32 * p] = qv[p].y;
            Qs[ak + 2][ar + 32 * p] = qv[p].z;
            Qs[ak + 3][ar + 32 * p] = qv[p].w;
            Ks[ak + 0][ar + 32 * p] = kv[p].x;
            Ks[ak + 1][ar + 32 * p] = kv[p].y;
            Ks[ak + 2][ar + 32 * p] = kv[p].z;
            Ks[ak + 3][ar + 32 * p] = kv[p].w;
        }
        __syncthreads();
        #pragma unroll
        for (int kk = 0; kk < 32; kk++) {
            float a[8], bb_[8];
            *(float4*)&a[0] = *(const float4*)&Qs[kk][tr];
            *(float4*)&a[4] = *(const float4*)&Qs[kk][tr + 4];
            *(float4*)&bb_[0] = *(const float4*)&Ks[kk][tc];
            *(float4*)&bb_[4] = *(const float4*)&Ks[kk][tc + 4];
            #pragma unroll
            for (int i = 0; i < 8; i++)
                #pragma unroll
                for (int j = 0; j < 8; j++) acc[i][j] += a[i] * bb_[j];
        }
    }
    #pragma unroll
    for (int i = 0; i < 8; i++) {
        float o[8];
        #pragma unroll
        for (int j = 0; j < 8; j++) o[j] = acc[i][j] * INV_SQRT_D;
        *(float4*)&Sb[(size_t)(r0 + tr + i) * S + c0 + tc] = *(float4*)&o[0];
        *(float4*)&Sb[(size_t)(r0 + tr + i) * S + c0 + tc + 4] = *(float4*)&o[4];
    }
}

// K9b: in-place row softmax on Smat. One wave per row; 4 rows/block.
__global__ void k_smax(float* __restrict__ Smat) {
    int row = blockIdx.x * 4 + (threadIdx.x >> 6);
    int lane = threadIdx.x & 63;
    float* p = Smat + (size_t)row * S;
    float4 v0 = *(const float4*)&p[lane * 4];
    float4 v1 = *(const float4*)&p[256 + lane * 4];
    float m = fmaxf(fmaxf(fmaxf(v0.x, v0.y), fmaxf(v0.z, v0.w)),
                    fmaxf(fmaxf(v1.x, v1.y), fmaxf(v1.z, v1.w)));
    #pragma unroll
    for (int off = 32; off; off >>= 1) m = fmaxf(m, __shfl_xor(m, off, 64));
    v0.x = expf(v0.x - m); v0.y = expf(v0.y - m);
    v0.z = expf(v0.z - m); v0.w = expf(v0.w - m);
    v1.x = expf(v1.x - m); v1.y = expf(v1.y - m);
    v1.z = expf(v1.z - m); v1.w = expf(v1.w - m);
    float s = v0.x + v0.y + v0.z + v0.w + v1.x + v1.y + v1.z + v1.w;
    #pragma unroll
    for (int off = 32; off; off >>= 1) s += __shfl_xor(s, off, 64);
    float inv = 1.0f / s;
    v0.x *= inv; v0.y *= inv; v0.z *= inv; v0.w *= inv;
    v1.x *= inv; v1.y *= inv; v1.z *= inv; v1.w *= inv;
    *(float4*)&p[lane * 4] = v0;
    *(float4*)&p[256 + lane * 4] = v1;
}

// ---------------------------------------------------------------------------
// K1: gather entity spans -> e_fea [B,T,E,H], feas = mean over E [B,T,H]
__global__ void k_gather(const float* __restrict__ xs,
                         const int* __restrict__ spans,
                         float* __restrict__ e_fea, float* __restrict__ feas) {
    int bt = blockIdx.x;
    int b = bt / T;
    int span = spans[bt];
    for (int h = threadIdx.x; h < H; h += 256) {
        float acc = 0.f;
        for (int e = 0; e < E; e++) {
            float v = xs[((size_t)b * S + span + e) * H + h];
            e_fea[((size_t)bt * E + e) * H + h] = v;
            acc += v;
        }
        feas[(size_t)bt * H + h] = acc * (1.0f / E);
    }
}

// ---------------------------------------------------------------------------
// K2: q = e_fea @ Wq + bq   [B*T*E, D]  (tiny: 256 rows)
__global__ void k_qproj(const float* __restrict__ e_fea,
                        const float* __restrict__ Wq,
                        const float* __restrict__ bq,
                        float* __restrict__ q) {
    int row = blockIdx.x;
    int d = threadIdx.x;
    const float* er = e_fea + (size_t)row * H;
    float acc = bq[d];
    #pragma unroll 4
    for (int h = 0; h < H; h++) acc += er[h] * Wq[(size_t)h * D + d];
    q[(size_t)row * D + d] = acc;
}

// ---------------------------------------------------------------------------
// K2b (R2 new): qk[bt,e,h] = sum_d q[bt,e,d]*Wk[h,d];  qb0[bt,e] = q[bt,e,:].bk
// Reassociation that KILLS k_kproj (was 229 us, 12.9 GF): logits over neighbors
// become qk . neigh rows (805 MF) instead of q . (neigh@Wk) (12.9 GF + 67 MB
// kbuf traffic). grid (B*T, 3), 256 threads; h = y*256+tid.
__global__ void k_qkw(const float* __restrict__ q, const float* __restrict__ Wk,
                      const float* __restrict__ bk,
                      float* __restrict__ qkb, float* __restrict__ qb0) {
    __shared__ float q_s[E * D];   // 4 KB
    const int bt = blockIdx.x;
    const float* qp = q + (size_t)bt * E * D;
    for (int i = threadIdx.x; i < E * D; i += 256) q_s[i] = qp[i];
    __syncthreads();
    const int h = blockIdx.y * 256 + threadIdx.x;
    float acc[E];
    #pragma unroll
    for (int e = 0; e < E; e++) acc[e] = 0.f;
    const float* wrow = Wk + (size_t)h * D;
    for (int d = 0; d < D; d += 4) {
        float4 wv = *(const float4*)&wrow[d];
        #pragma unroll
        for (int e = 0; e < E; e++) {
            float4 qv = *(const float4*)&q_s[e * D + d];
            acc[e] += qv.x * wv.x + qv.y * wv.y + qv.z * wv.z + qv.w * wv.w;
        }
    }
    #pragma unroll
    for (int e = 0; e < E; e++)
        qkb[((size_t)bt * E + e) * H + h] = acc[e];
    if (blockIdx.y == 0 && threadIdx.x < E) {
        int e = threadIdx.x;
        float s = 0.f;
        for (int d = 0; d < D; d++) s += q_s[e * D + d] * bk[d];
        qb0[bt * E + e] = s;
    }
}

// ---------------------------------------------------------------------------
// K4 (R2 rewrite): per (b,t,n): logits[e,l] = (qk[bt,e,:].neigh[btn,l,:] +
// qb0[bt,e]) * inv_sqrt_d; softmax over l; attn_p out; pooled = abar @ neigh.
// neigh streamed twice (logits via LDS chunks, pooled direct) — 201 MB fits
// L3 so pass 2 is mostly Infinity-Cache hits. LDS 44.6 KB -> 3 blocks/CU.
// n_s row-stride 69 (gcd(5,32)=1) -> conflict-free lane-l reads; qk_s reads
// are wave-uniform broadcasts (float4).
__global__ void k_sdpa(const float* __restrict__ qkb, const float* __restrict__ qb0,
                       const float* __restrict__ neigh,
                       float* __restrict__ attn_p, float* __restrict__ pooled) {
    __shared__ float qk_s[E * H];      // 24,576 B
    __shared__ float u_s[64 * 69];     // 17,664 B: n_s chunk; later red[4][64][8]
    __shared__ float attn_s[E * L];    //  2,048 B
    __shared__ float abar_s[L];
    __shared__ float qb0_s[E];
    const int btn = blockIdx.x;
    const int bt = btn >> 5;           // / N
    const float* qkp = qkb + (size_t)bt * E * H;
    const float* nrow = neigh + (size_t)btn * L * H;
    const int tid = threadIdx.x;
    const int l = tid & 63;            // lane -> neighbor token
    const int g = tid >> 6;            // wave -> 16-wide h-slice

    for (int i = tid; i < E * H / 4; i += 256)
        *(float4*)&qk_s[i * 4] = *(const float4*)&qkp[i * 4];
    if (tid < E) qb0_s[tid] = qb0[bt * E + tid];

    float acc[E];
    #pragma unroll
    for (int e = 0; e < E; e++) acc[e] = 0.f;

    for (int c = 0; c < H / 64; c++) {       // 12 chunks of 64 h
        const int h0 = c * 64;
        __syncthreads();                     // n_s free (also covers qk_s stage)
        for (int i = tid; i < 64 * 64; i += 256) {
            int ll = i >> 6, hh = i & 63;
            u_s[ll * 69 + hh] = nrow[(size_t)ll * H + h0 + hh];
        }
        __syncthreads();
        const int hb = g * 16;
        #pragma unroll
        for (int h = 0; h < 16; h += 4) {
            float n0 = u_s[l * 69 + hb + h + 0];
            float n1 = u_s[l * 69 + hb + h + 1];
            float n2 = u_s[l * 69 + hb + h + 2];
            float n3 = u_s[l * 69 + hb + h + 3];
            #pragma unroll
            for (int e = 0; e < E; e++) {
                float4 qv = *(const float4*)&qk_s[e * H + h0 + hb + h];
                acc[e] += qv.x * n0 + qv.y * n1 + qv.z * n2 + qv.w * n3;
            }
        }
    }
    __syncthreads();                         // last compute done; u_s -> red
    float* red = u_s;                        // red[g*512 + l*8 + e]
    *(float4*)&red[g * 512 + l * 8 + 0] = make_float4(acc[0], acc[1], acc[2], acc[3]);
    *(float4*)&red[g * 512 + l * 8 + 4] = make_float4(acc[4], acc[5], acc[6], acc[7]);
    __syncthreads();
    for (int p = tid; p < E * L; p += 256) {
        int e = p >> 6, ll = p & 63;
        float s = red[ll * 8 + e] + red[512 + ll * 8 + e] +
                  red[1024 + ll * 8 + e] + red[1536 + ll * 8 + e];
        attn_s[e * L + ll] = (s + qb0_s[e]) * INV_SQRT_D;
    }
    __syncthreads();

    if (tid < E) {
        int e = tid;
        float m = -1e30f;
        for (int ll = 0; ll < L; ll++) m = fmaxf(m, attn_s[e * L + ll]);
        float ssum = 0.f;
        for (int ll = 0; ll < L; ll++) {
            float ex = expf(attn_s[e * L + ll] - m);
            attn_s[e * L + ll] = ex;
            ssum += ex;
        }
        float inv = 1.0f / ssum;
        for (int ll = 0; ll < L; ll++) attn_s[e * L + ll] *= inv;
    }
    __syncthreads();

    for (int i = tid; i < E * L; i += 256)
        attn_p[(size_t)btn * E * L + i] = attn_s[i];
    if (tid < L) {
        float s = 0.f;
        #pragma unroll
        for (int e = 0; e < E; e++) s += attn_s[e * L + tid];
        abar_s[tid] = s * (1.0f / E);
    }
    __syncthreads();

    for (int h = tid; h < H; h += 256) {
        float acc2 = 0.f;
        for (int ll = 0; ll < L; ll++) acc2 += abar_s[ll] * nrow[(size_t)ll * H + h];
        pooled[(size_t)btn * H + h] = acc2;
    }
}

// ---------------------------------------------------------------------------
// K5a: fold Ww/Wa/bw/ba/wb/bb into misc
__global__ void k_uv(const float* __restrict__ Ww, const float* __restrict__ bw,
                     const float* __restrict__ Wa, const float* __restrict__ ba,
                     const float* __restrict__ wb, const float* __restrict__ bb,
                     float* __restrict__ misc) {
    int h = blockIdx.x * blockDim.x + threadIdx.x;
    if (h < H) {
        float lo = 0.f, hi = 0.f;
        for (int a = 0; a < A; a++) {
            float w = Ww[(size_t)h * A + a];
            lo += w * Wa[a];
            hi += w * Wa[A + a];
        }
        misc[h] = lo;
        misc[H + h] = hi;
    }
    if (blockIdx.x == 0 && threadIdx.x == 0) {
        float c = ba[0];
        for (int a = 0; a < A; a++) c += bw[a] * (Wa[a] + Wa[A + a]);
        misc[2 * H] = c;
        misc[2 * H + 1] = wb[0];
        misc[2 * H + 2] = bb[0];
    }
}

// ---------------------------------------------------------------------------
// K5b: score[btn] = sigmoid(leaky(feas@v + pooled@u + c0) + dist*wb + bb)
__global__ void k_score(const float* __restrict__ feas, const float* __restrict__ pooled,
                        const float* __restrict__ misc, const float* __restrict__ dists,
                        float* __restrict__ score) {
    __shared__ float red[4];
    int btn = blockIdx.x;
    int bt = btn / N;
    float part = 0.f;
    for (int h = threadIdx.x; h < H; h += 256)
        part += feas[(size_t)bt * H + h] * misc[h] + pooled[(size_t)btn * H + h] * misc[H + h];
    #pragma unroll
    for (int off = 32; off > 0; off >>= 1) part += __shfl_down(part, off, 64);
    if ((threadIdx.x & 63) == 0) red[threadIdx.x >> 6] = part;
    __syncthreads();
    if (threadIdx.x == 0) {
        float tot = red[0] + red[1] + red[2] + red[3] + misc[2 * H];
        float lk = tot > 0.f ? tot : 0.01f * tot;
        float xatt = lk + dists[btn] * misc[2 * H + 1] + misc[2 * H + 2];
        score[btn] = 1.0f / (1.0f + expf(-xatt));
    }
}

// ---------------------------------------------------------------------------
// K6: delta[bt,e,h] += sum_{n, l-chunk} score_n * attn_p[n,e,l] * neigh[l,h]
__global__ void k_delta(const float* __restrict__ attn_p, const float* __restrict__ score,
                        const float* __restrict__ neigh, float* __restrict__ delta) {
    __shared__ float w_s[E * 8];
    int bt = blockIdx.x, l0 = blockIdx.y * 8;
    float acc[E][3];
    #pragma unroll
    for (int e = 0; e < E; e++)
        #pragma unroll
        for (int c = 0; c < 3; c++) acc[e][c] = 0.f;
    for (int n = 0; n < N; n++) {
        int btn = bt * N + n;
        if (threadIdx.x < E * 8) {
            int e = threadIdx.x >> 3, lp = threadIdx.x & 7;
            w_s[threadIdx.x] = score[btn] * attn_p[((size_t)btn * E + e) * L + l0 + lp];
        }
        __syncthreads();
        const float* nrow = neigh + ((size_t)btn * L + l0) * H;
        for (int lp = 0; lp < 8; lp++) {
            float nv[3];
            #pragma unroll
            for (int c = 0; c < 3; c++) nv[c] = nrow[(size_t)lp * H + threadIdx.x + c * 256];
            #pragma unroll
            for (int e = 0; e < E; e++) {
                float w = w_s[e * 8 + lp];
                #pragma unroll
                for (int c = 0; c < 3; c++) acc[e][c] += w * nv[c];
            }
        }
        __syncthreads();
    }
    #pragma unroll
    for (int e = 0; e < E; e++)
        #pragma unroll
        for (int c = 0; c < 3; c++)
            atomicAdd(&delta[((size_t)bt * E + e) * H + threadIdx.x + c * 256], acc[e][c]);
}

// ---------------------------------------------------------------------------
// K7: x[b, span+e, h] += delta[bt,e,h]  (atomic: T spans may overlap)
__global__ void k_addspan(const float* __restrict__ delta, const int* __restrict__ spans,
                          float* __restrict__ x) {
    int i = blockIdx.x * 256 + threadIdx.x;
    int h = i % H;
    int e = (i / H) % E;
    int bt = i / (H * E);
    int b = bt / T;
    atomicAdd(&x[((size_t)b * S + spans[bt] + e) * H + h], delta[i]);
}

// ---------------------------------------------------------------------------
// K8b: v2 = x@Wv+bv IN-PLACE over x. Block owns 16 rows exclusively: stages
// them transposed in LDS ([h][r], stride 20 -> 16B-aligned rows), then
// overwrites. In-place safe (each block reads only rows it staged).
// R1: 768 threads (12 waves) share the 61.4KB stage -> 24 waves/CU; thread t
// owns output column t; 8-deep Wv prefetch; launch_bounds pins VGPR<=64.
__global__ __launch_bounds__(768, 8) void k_v2(float* __restrict__ xv,
                                               const float* __restrict__ Wv,
                                               const float* __restrict__ bv) {
    __shared__ float x_s[H * 20];   // 61,440 B: [h][r], row-stride 20
    const int r0 = blockIdx.x * 16;
    const int t = threadIdx.x;      // 0..767 = h-index for staging, out col
    #pragma unroll
    for (int j = 0; j < 16; j++)
        x_s[t * 20 + j] = xv[(size_t)(r0 + j) * H + t];
    __syncthreads();

    float acc[16];
    #pragma unroll
    for (int r = 0; r < 16; r++) acc[r] = 0.f;

    const float* wp = Wv + t;
    for (int h = 0; h < H; h += 8) {
        float w[8];
        #pragma unroll
        for (int u = 0; u < 8; u++) w[u] = wp[(size_t)(h + u) * H];
        #pragma unroll
        for (int u = 0; u < 8; u++) {
            float4 a0 = *(const float4*)&x_s[(h + u) * 20 + 0];
            float4 a1 = *(const float4*)&x_s[(h + u) * 20 + 4];
            float4 a2 = *(const float4*)&x_s[(h + u) * 20 + 8];
            float4 a3 = *(const float4*)&x_s[(h + u) * 20 + 12];
            acc[0]  += a0.x * w[u]; acc[1]  += a0.y * w[u];
            acc[2]  += a0.z * w[u]; acc[3]  += a0.w * w[u];
            acc[4]  += a1.x * w[u]; acc[5]  += a1.y * w[u];
            acc[6]  += a1.z * w[u]; acc[7]  += a1.w * w[u];
            acc[8]  += a2.x * w[u]; acc[9]  += a2.y * w[u];
            acc[10] += a2.z * w[u]; acc[11] += a2.w * w[u];
            acc[12] += a3.x * w[u]; acc[13] += a3.y * w[u];
            acc[14] += a3.z * w[u]; acc[15] += a3.w * w[u];
        }
    }
    const float bias = bv[t];
    #pragma unroll
    for (int r = 0; r < 16; r++)
        xv[(size_t)(r0 + r) * H + t] = acc[r] + bias;
}

// ---------------------------------------------------------------------------
extern "C" void kernel_launch(void* const* d_in, const int* in_sizes, int n_in,
                              void* d_out, int out_size, void* d_ws, size_t ws_size,
                              hipStream_t stream) {
    const float* xs    = (const float*)d_in[0];
    const float* neigh = (const float*)d_in[1];
    const float* dists = (const float*)d_in[2];
    const int*   spans = (const int*)d_in[3];
    const float* Wq = (const float*)d_in[4];
    const float* bq = (const float*)d_in[5];
    const float* Wk = (const float*)d_in[6];
    const float* bk = (const float*)d_in[7];
    const float* Wv = (const float*)d_in[8];
    const float* bv = (const float*)d_in[9];
    const float* Ww = (const float*)d_in[10];
    const float* bw = (const float*)d_in[11];
    const float* Wa = (const float*)d_in[12];
    const float* ba = (const float*)d_in[13];
    const float* wb = (const float*)d_in[14];
    const float* bb = (const float*)d_in[15];
    float* out = (float*)d_out;

    // Workspace layout (fp32), total 12,582,912 floats = 48 MiB.
    // Region A [0, 8388608): x [B,S,H] (6,291,456) | q2 | k2; v2 in-place on x.
    //   (kbuf is GONE — k_kproj eliminated by the qk reassociation.)
    // Region B [8388608, 12582912): early-phase smalls (attn_p..qb0b,
    //   1,961,216 floats, all dead before k_qkT) -> then Smat [B,S,S] (4,194,304).
    float* ws     = (float*)d_ws;
    float* regB   = ws + (size_t)8388608;
    float* attn_p = regB;                                 //   524,288
    float* pooled = attn_p + (size_t)B * T * N * E * L;   //   786,432
    float* delta  = pooled + (size_t)B * T * N * H;       //   196,608
    float* e_fea  = delta + (size_t)B * T * E * H;        //   196,608
    float* qb     = e_fea + (size_t)B * T * E * H;        //    32,768
    float* feas   = qb + (size_t)B * T * E * D;           //    24,576
    float* misc   = feas + (size_t)B * T * H;             //     2,048
    float* scoreb = misc + 2048;                          //     1,024
    float* qkb    = scoreb + 1024;                        //   196,608
    float* qb0b   = qkb + (size_t)B * T * E * H;          //       256
    float* x      = ws;                                   // region A
    float* q2     = ws + (size_t)B * S * H;               // alias
    float* k2     = q2 + (size_t)B * S * D;               // alias
    float* v2     = x;                                    // in-place
    float* Smat   = regB;                                 // alias (smalls dead)

    k_gather<<<B * T, 256, 0, stream>>>(xs, spans, e_fea, feas);
    k_qproj<<<B * T * E, D, 0, stream>>>(e_fea, Wq, bq, qb);
    k_qkw<<<dim3(B * T, 3), 256, 0, stream>>>(qb, Wk, bk, qkb, qb0b);
    k_sdpa<<<B * T * N, 256, 0, stream>>>(qkb, qb0b, neigh, attn_p, pooled);
    k_uv<<<3, 256, 0, stream>>>(Ww, bw, Wa, ba, wb, bb, misc);
    k_score<<<B * T * N, 256, 0, stream>>>(feas, pooled, misc, dists, scoreb);
    hipMemsetAsync(delta, 0, (size_t)B * T * E * H * sizeof(float), stream);
    k_delta<<<dim3(B * T, L / 8), 256, 0, stream>>>(attn_p, scoreb, neigh, delta);
    hipMemcpyAsync(x, xs, (size_t)B * S * H * sizeof(float), hipMemcpyDeviceToDevice, stream);
    k_addspan<<<(B * T * E * H) / 256, 256, 0, stream>>>(delta, spans, x);
    k_qk2<<<dim3(B * S / 128, 2), 256, 0, stream>>>(x, Wq, bq, Wk, bk, q2, k2);
    k_v2<<<B * S / 16, 768, 0, stream>>>(v2, Wv, bv);
    k_qkT<<<dim3(S / 128, S / 128, B), 256, 0, stream>>>(q2, k2, Smat);
    k_smax<<<B * S / 4, 256, 0, stream>>>(Smat);
    k_pv<<<dim3(S / 128, H / 128, B), 256, 0, stream>>>(Smat, v2, out);
}

// Round 3
// 1011.160 us; speedup vs baseline: 1.2389x; 1.0313x over previous
//
#include <hip/hip_runtime.h>
#include <hip/hip_bf16.h>

// Problem constants (GeoUmpForPretrain) — all tensors fp32 per reference.
constexpr int B = 16, S = 512, H = 768, T = 2, N = 32, L = 64, E = 8, D = 128, A = 128;
constexpr float INV_SQRT_D = 0.08838834764831843f;  // 1/sqrt(128)

// ---------------------------------------------------------------------------
// Tiled fp32 GEMM core: C[r0:r0+128, c0:c0+128] = A @ W (+ bias)
// A: [M,K] row-major (lda); W: [K,N] row-major (ldw); C row-major (ldc).
// 256 threads, 8x8 outputs/thread, BK=32. K must be a multiple of 32.
// bias may be nullptr. One call site per kernel (one LDS allocation).
__device__ __forceinline__ void gemm128(const float* __restrict__ Ap, int lda,
                                        const float* __restrict__ W, int ldw,
                                        const float* __restrict__ bias,
                                        float* __restrict__ C, int ldc,
                                        int r0, int c0, int K) {
    __shared__ float As[32][132];   // [kk][row], row-stride 132 (16B-aligned rows)
    __shared__ float Ws[32][128];   // [kk][col]
    const int tid = threadIdx.x;
    const int tr = (tid >> 4) << 3;          // 0,8,...,120
    const int tc = (tid & 15) << 3;          // 0,8,...,120
    float acc[8][8];
    #pragma unroll
    for (int i = 0; i < 8; i++)
        #pragma unroll
        for (int j = 0; j < 8; j++) acc[i][j] = 0.f;

    const int ar = tid >> 3;                 // 0..31  (A tile row base)
    const int ak = (tid & 7) << 2;           // 0..28  (A tile col, float4)
    const int wr = tid >> 5;                 // 0..7   (W tile row base)
    const int wc = (tid & 31) << 2;          // 0..124 (W tile col, float4)

    for (int k0 = 0; k0 < K; k0 += 32) {
        float4 av[4], wv[4];
        #pragma unroll
        for (int p = 0; p < 4; p++) {
            av[p] = *(const float4*)&Ap[(size_t)(r0 + ar + 32 * p) * lda + k0 + ak];
            wv[p] = *(const float4*)&W[(size_t)(k0 + wr + 8 * p) * ldw + c0 + wc];
        }
        __syncthreads();   // previous tile's LDS reads done
        #pragma unroll
        for (int p = 0; p < 4; p++) {
            As[ak + 0][ar + 32 * p] = av[p].x;
            As[ak + 1][ar + 32 * p] = av[p].y;
            As[ak + 2][ar + 32 * p] = av[p].z;
            As[ak + 3][ar + 32 * p] = av[p].w;
            *(float4*)&Ws[wr + 8 * p][wc] = wv[p];
        }
        __syncthreads();
        #pragma unroll
        for (int kk = 0; kk < 32; kk++) {
            float a[8], b[8];
            *(float4*)&a[0] = *(const float4*)&As[kk][tr];
            *(float4*)&a[4] = *(const float4*)&As[kk][tr + 4];
            *(float4*)&b[0] = *(const float4*)&Ws[kk][tc];
            *(float4*)&b[4] = *(const float4*)&Ws[kk][tc + 4];
            #pragma unroll
            for (int i = 0; i < 8; i++)
                #pragma unroll
                for (int j = 0; j < 8; j++) acc[i][j] += a[i] * b[j];
        }
    }
    #pragma unroll
    for (int i = 0; i < 8; i++) {
        float o[8];
        #pragma unroll
        for (int j = 0; j < 8; j++)
            o[j] = acc[i][j] + (bias ? bias[c0 + tc + j] : 0.f);
        *(float4*)&C[(size_t)(r0 + tr + i) * ldc + c0 + tc] = *(float4*)&o[0];
        *(float4*)&C[(size_t)(r0 + tr + i) * ldc + c0 + tc + 4] = *(float4*)&o[4];
    }
}

// K8a: q2 = x@Wq+bq (y=0), k2 = x@Wk+bk (y=1).  grid (64, 2)
__global__ void k_qk2(const float* __restrict__ x,
                      const float* __restrict__ Wq, const float* __restrict__ bq,
                      const float* __restrict__ Wk, const float* __restrict__ bk,
                      float* __restrict__ q2, float* __restrict__ k2) {
    const float* W = blockIdx.y ? Wk : Wq;
    const float* bs = blockIdx.y ? bk : bq;
    float* C = blockIdx.y ? k2 : q2;
    gemm128(x, H, W, D, bs, C, D, blockIdx.x * 128, 0, H);
}

// K9c: out[b] = P[b] @ v2[b].  grid (4, 6, 16)
__global__ void k_pv(const float* __restrict__ P, const float* __restrict__ v2,
                     float* __restrict__ out) {
    int b = blockIdx.z;
    gemm128(P + (size_t)b * S * S, S, v2 + (size_t)b * S * H, H, nullptr,
            out + (size_t)b * S * H, H, blockIdx.x * 128, blockIdx.y * 128, S);
}

// ---------------------------------------------------------------------------
// K9a: Smat[b] = q2[b] @ k2[b]^T * INV_SQRT_D.  grid (4, 4, 16).
// Both operands staged K-major in LDS (B is transposed by staging).
__global__ void k_qkT(const float* __restrict__ q2, const float* __restrict__ k2,
                      float* __restrict__ Smat) {
    __shared__ float Qs[32][132];
    __shared__ float Ks[32][132];
    const int b = blockIdx.z;
    const int r0 = blockIdx.x * 128, c0 = blockIdx.y * 128;
    const float* Qb = q2 + (size_t)b * S * D;
    const float* Kb = k2 + (size_t)b * S * D;
    float* Sb = Smat + (size_t)b * S * S;
    const int tid = threadIdx.x;
    const int tr = (tid >> 4) << 3;
    const int tc = (tid & 15) << 3;
    const int ar = tid >> 3;             // 0..31
    const int ak = (tid & 7) << 2;       // 0..28
    float acc[8][8];
    #pragma unroll
    for (int i = 0; i < 8; i++)
        #pragma unroll
        for (int j = 0; j < 8; j++) acc[i][j] = 0.f;

    for (int k0 = 0; k0 < D; k0 += 32) {
        float4 qv[4], kv[4];
        #pragma unroll
        for (int p = 0; p < 4; p++) {
            qv[p] = *(const float4*)&Qb[(size_t)(r0 + ar + 32 * p) * D + k0 + ak];
            kv[p] = *(const float4*)&Kb[(size_t)(c0 + ar + 32 * p) * D + k0 + ak];
        }
        __syncthreads();
        #pragma unroll
        for (int p = 0; p < 4; p++) {
            Qs[ak + 0][ar + 32 * p] = qv[p].x;
            Qs[ak + 1][ar + 32 * p] = qv[p].y;
            Qs[ak + 2][ar + 32 * p] = qv[p].z;
            Qs[ak + 3][ar + 32 * p] = qv[p].w;
            Ks[ak + 0][ar + 32 * p] = kv[p].x;
            Ks[ak + 1][ar + 32 * p] = kv[p].y;
            Ks[ak + 2][ar + 32 * p] = kv[p].z;
            Ks[ak + 3][ar + 32 * p] = kv[p].w;
        }
        __syncthreads();
        #pragma unroll
        for (int kk = 0; kk < 32; kk++) {
            float a[8], bb_[8];
            *(float4*)&a[0] = *(const float4*)&Qs[kk][tr];
            *(float4*)&a[4] = *(const float4*)&Qs[kk][tr + 4];
            *(float4*)&bb_[0] = *(const float4*)&Ks[kk][tc];
            *(float4*)&bb_[4] = *(const float4*)&Ks[kk][tc + 4];
            #pragma unroll
            for (int i = 0; i < 8; i++)
                #pragma unroll
                for (int j = 0; j < 8; j++) acc[i][j] += a[i] * bb_[j];
        }
    }
    #pragma unroll
    for (int i = 0; i < 8; i++) {
        float o[8];
        #pragma unroll
        for (int j = 0; j < 8; j++) o[j] = acc[i][j] * INV_SQRT_D;
        *(float4*)&Sb[(size_t)(r0 + tr + i) * S + c0 + tc] = *(float4*)&o[0];
        *(float4*)&Sb[(size_t)(r0 + tr + i) * S + c0 + tc + 4] = *(float4*)&o[4];
    }
}

// K9b: in-place row softmax on Smat. One wave per row; 4 rows/block.
__global__ void k_smax(float* __restrict__ Smat) {
    int row = blockIdx.x * 4 + (threadIdx.x >> 6);
    int lane = threadIdx.x & 63;
    float* p = Smat + (size_t)row * S;
    float4 v0 = *(const float4*)&p[lane * 4];
    float4 v1 = *(const float4*)&p[256 + lane * 4];
    float m = fmaxf(fmaxf(fmaxf(v0.x, v0.y), fmaxf(v0.z, v0.w)),
                    fmaxf(fmaxf(v1.x, v1.y), fmaxf(v1.z, v1.w)));
    #pragma unroll
    for (int off = 32; off; off >>= 1) m = fmaxf(m, __shfl_xor(m, off, 64));
    v0.x = expf(v0.x - m); v0.y = expf(v0.y - m);
    v0.z = expf(v0.z - m); v0.w = expf(v0.w - m);
    v1.x = expf(v1.x - m); v1.y = expf(v1.y - m);
    v1.z = expf(v1.z - m); v1.w = expf(v1.w - m);
    float s = v0.x + v0.y + v0.z + v0.w + v1.x + v1.y + v1.z + v1.w;
    #pragma unroll
    for (int off = 32; off; off >>= 1) s += __shfl_xor(s, off, 64);
    float inv = 1.0f / s;
    v0.x *= inv; v0.y *= inv; v0.z *= inv; v0.w *= inv;
    v1.x *= inv; v1.y *= inv; v1.z *= inv; v1.w *= inv;
    *(float4*)&p[lane * 4] = v0;
    *(float4*)&p[256 + lane * 4] = v1;
}

// ---------------------------------------------------------------------------
// K1: gather entity spans -> e_fea [B,T,E,H], feas = mean over E [B,T,H]
__global__ void k_gather(const float* __restrict__ xs,
                         const int* __restrict__ spans,
                         float* __restrict__ e_fea, float* __restrict__ feas) {
    int bt = blockIdx.x;
    int b = bt / T;
    int span = spans[bt];
    for (int h = threadIdx.x; h < H; h += 256) {
        float acc = 0.f;
        for (int e = 0; e < E; e++) {
            float v = xs[((size_t)b * S + span + e) * H + h];
            e_fea[((size_t)bt * E + e) * H + h] = v;
            acc += v;
        }
        feas[(size_t)bt * H + h] = acc * (1.0f / E);
    }
}

// ---------------------------------------------------------------------------
// K2: q = e_fea @ Wq + bq   [B*T*E, D]  (tiny: 256 rows)
__global__ void k_qproj(const float* __restrict__ e_fea,
                        const float* __restrict__ Wq,
                        const float* __restrict__ bq,
                        float* __restrict__ q) {
    int row = blockIdx.x;
    int d = threadIdx.x;
    const float* er = e_fea + (size_t)row * H;
    float acc = bq[d];
    #pragma unroll 4
    for (int h = 0; h < H; h++) acc += er[h] * Wq[(size_t)h * D + d];
    q[(size_t)row * D + d] = acc;
}

// ---------------------------------------------------------------------------
// K2b: qk[bt,e,h] = sum_d q[bt,e,d]*Wk[h,d];  qb0[bt,e] = q[bt,e,:].bk
// Reassociation that killed k_kproj: logits over neighbors become
// qk . neigh rows (805 MF) instead of q . (neigh@Wk) (12.9 GF + 67 MB traffic).
__global__ void k_qkw(const float* __restrict__ q, const float* __restrict__ Wk,
                      const float* __restrict__ bk,
                      float* __restrict__ qkb, float* __restrict__ qb0) {
    __shared__ float q_s[E * D];   // 4 KB
    const int bt = blockIdx.x;
    const float* qp = q + (size_t)bt * E * D;
    for (int i = threadIdx.x; i < E * D; i += 256) q_s[i] = qp[i];
    __syncthreads();
    const int h = blockIdx.y * 256 + threadIdx.x;
    float acc[E];
    #pragma unroll
    for (int e = 0; e < E; e++) acc[e] = 0.f;
    const float* wrow = Wk + (size_t)h * D;
    for (int d = 0; d < D; d += 4) {
        float4 wv = *(const float4*)&wrow[d];
        #pragma unroll
        for (int e = 0; e < E; e++) {
            float4 qv = *(const float4*)&q_s[e * D + d];
            acc[e] += qv.x * wv.x + qv.y * wv.y + qv.z * wv.z + qv.w * wv.w;
        }
    }
    #pragma unroll
    for (int e = 0; e < E; e++)
        qkb[((size_t)bt * E + e) * H + h] = acc[e];
    if (blockIdx.y == 0 && threadIdx.x < E) {
        int e = threadIdx.x;
        float s = 0.f;
        for (int d = 0; d < D; d++) s += q_s[e * D + d] * bk[d];
        qb0[bt * E + e] = s;
    }
}

// ---------------------------------------------------------------------------
// K4: per (b,t,n): logits[e,l] = (qk[bt,e,:].neigh[btn,l,:] + qb0[bt,e]) *
// inv_sqrt_d; softmax over l; attn_p out; pooled = abar @ neigh.
__global__ void k_sdpa(const float* __restrict__ qkb, const float* __restrict__ qb0,
                       const float* __restrict__ neigh,
                       float* __restrict__ attn_p, float* __restrict__ pooled) {
    __shared__ float qk_s[E * H];      // 24,576 B
    __shared__ float u_s[64 * 69];     // 17,664 B: n_s chunk; later red[4][64][8]
    __shared__ float attn_s[E * L];    //  2,048 B
    __shared__ float abar_s[L];
    __shared__ float qb0_s[E];
    const int btn = blockIdx.x;
    const int bt = btn >> 5;           // / N
    const float* qkp = qkb + (size_t)bt * E * H;
    const float* nrow = neigh + (size_t)btn * L * H;
    const int tid = threadIdx.x;
    const int l = tid & 63;            // lane -> neighbor token
    const int g = tid >> 6;            // wave -> 16-wide h-slice

    for (int i = tid; i < E * H / 4; i += 256)
        *(float4*)&qk_s[i * 4] = *(const float4*)&qkp[i * 4];
    if (tid < E) qb0_s[tid] = qb0[bt * E + tid];

    float acc[E];
    #pragma unroll
    for (int e = 0; e < E; e++) acc[e] = 0.f;

    for (int c = 0; c < H / 64; c++) {       // 12 chunks of 64 h
        const int h0 = c * 64;
        __syncthreads();                     // n_s free (also covers qk_s stage)
        for (int i = tid; i < 64 * 64; i += 256) {
            int ll = i >> 6, hh = i & 63;
            u_s[ll * 69 + hh] = nrow[(size_t)ll * H + h0 + hh];
        }
        __syncthreads();
        const int hb = g * 16;
        #pragma unroll
        for (int h = 0; h < 16; h += 4) {
            float n0 = u_s[l * 69 + hb + h + 0];
            float n1 = u_s[l * 69 + hb + h + 1];
            float n2 = u_s[l * 69 + hb + h + 2];
            float n3 = u_s[l * 69 + hb + h + 3];
            #pragma unroll
            for (int e = 0; e < E; e++) {
                float4 qv = *(const float4*)&qk_s[e * H + h0 + hb + h];
                acc[e] += qv.x * n0 + qv.y * n1 + qv.z * n2 + qv.w * n3;
            }
        }
    }
    __syncthreads();                         // last compute done; u_s -> red
    float* red = u_s;                        // red[g*512 + l*8 + e]
    *(float4*)&red[g * 512 + l * 8 + 0] = make_float4(acc[0], acc[1], acc[2], acc[3]);
    *(float4*)&red[g * 512 + l * 8 + 4] = make_float4(acc[4], acc[5], acc[6], acc[7]);
    __syncthreads();
    for (int p = tid; p < E * L; p += 256) {
        int e = p >> 6, ll = p & 63;
        float s = red[ll * 8 + e] + red[512 + ll * 8 + e] +
                  red[1024 + ll * 8 + e] + red[1536 + ll * 8 + e];
        attn_s[e * L + ll] = (s + qb0_s[e]) * INV_SQRT_D;
    }
    __syncthreads();

    if (tid < E) {
        int e = tid;
        float m = -1e30f;
        for (int ll = 0; ll < L; ll++) m = fmaxf(m, attn_s[e * L + ll]);
        float ssum = 0.f;
        for (int ll = 0; ll < L; ll++) {
            float ex = expf(attn_s[e * L + ll] - m);
            attn_s[e * L + ll] = ex;
            ssum += ex;
        }
        float inv = 1.0f / ssum;
        for (int ll = 0; ll < L; ll++) attn_s[e * L + ll] *= inv;
    }
    __syncthreads();

    for (int i = tid; i < E * L; i += 256)
        attn_p[(size_t)btn * E * L + i] = attn_s[i];
    if (tid < L) {
        float s = 0.f;
        #pragma unroll
        for (int e = 0; e < E; e++) s += attn_s[e * L + tid];
        abar_s[tid] = s * (1.0f / E);
    }
    __syncthreads();

    for (int h = tid; h < H; h += 256) {
        float acc2 = 0.f;
        for (int ll = 0; ll < L; ll++) acc2 += abar_s[ll] * nrow[(size_t)ll * H + h];
        pooled[(size_t)btn * H + h] = acc2;
    }
}

// ---------------------------------------------------------------------------
// K5a: fold Ww/Wa/bw/ba/wb/bb into misc
__global__ void k_uv(const float* __restrict__ Ww, const float* __restrict__ bw,
                     const float* __restrict__ Wa, const float* __restrict__ ba,
                     const float* __restrict__ wb, const float* __restrict__ bb,
                     float* __restrict__ misc) {
    int h = blockIdx.x * blockDim.x + threadIdx.x;
    if (h < H) {
        float lo = 0.f, hi = 0.f;
        for (int a = 0; a < A; a++) {
            float w = Ww[(size_t)h * A + a];
            lo += w * Wa[a];
            hi += w * Wa[A + a];
        }
        misc[h] = lo;
        misc[H + h] = hi;
    }
    if (blockIdx.x == 0 && threadIdx.x == 0) {
        float c = ba[0];
        for (int a = 0; a < A; a++) c += bw[a] * (Wa[a] + Wa[A + a]);
        misc[2 * H] = c;
        misc[2 * H + 1] = wb[0];
        misc[2 * H + 2] = bb[0];
    }
}

// ---------------------------------------------------------------------------
// K5b: score[btn] = sigmoid(leaky(feas@v + pooled@u + c0) + dist*wb + bb)
__global__ void k_score(const float* __restrict__ feas, const float* __restrict__ pooled,
                        const float* __restrict__ misc, const float* __restrict__ dists,
                        float* __restrict__ score) {
    __shared__ float red[4];
    int btn = blockIdx.x;
    int bt = btn / N;
    float part = 0.f;
    for (int h = threadIdx.x; h < H; h += 256)
        part += feas[(size_t)bt * H + h] * misc[h] + pooled[(size_t)btn * H + h] * misc[H + h];
    #pragma unroll
    for (int off = 32; off > 0; off >>= 1) part += __shfl_down(part, off, 64);
    if ((threadIdx.x & 63) == 0) red[threadIdx.x >> 6] = part;
    __syncthreads();
    if (threadIdx.x == 0) {
        float tot = red[0] + red[1] + red[2] + red[3] + misc[2 * H];
        float lk = tot > 0.f ? tot : 0.01f * tot;
        float xatt = lk + dists[btn] * misc[2 * H + 1] + misc[2 * H + 2];
        score[btn] = 1.0f / (1.0f + expf(-xatt));
    }
}

// ---------------------------------------------------------------------------
// K6: delta[bt,e,h] += sum_{n, l-chunk} score_n * attn_p[n,e,l] * neigh[l,h]
__global__ void k_delta(const float* __restrict__ attn_p, const float* __restrict__ score,
                        const float* __restrict__ neigh, float* __restrict__ delta) {
    __shared__ float w_s[E * 8];
    int bt = blockIdx.x, l0 = blockIdx.y * 8;
    float acc[E][3];
    #pragma unroll
    for (int e = 0; e < E; e++)
        #pragma unroll
        for (int c = 0; c < 3; c++) acc[e][c] = 0.f;
    for (int n = 0; n < N; n++) {
        int btn = bt * N + n;
        if (threadIdx.x < E * 8) {
            int e = threadIdx.x >> 3, lp = threadIdx.x & 7;
            w_s[threadIdx.x] = score[btn] * attn_p[((size_t)btn * E + e) * L + l0 + lp];
        }
        __syncthreads();
        const float* nrow = neigh + ((size_t)btn * L + l0) * H;
        for (int lp = 0; lp < 8; lp++) {
            float nv[3];
            #pragma unroll
            for (int c = 0; c < 3; c++) nv[c] = nrow[(size_t)lp * H + threadIdx.x + c * 256];
            #pragma unroll
            for (int e = 0; e < E; e++) {
                float w = w_s[e * 8 + lp];
                #pragma unroll
                for (int c = 0; c < 3; c++) acc[e][c] += w * nv[c];
            }
        }
        __syncthreads();
    }
    #pragma unroll
    for (int e = 0; e < E; e++)
        #pragma unroll
        for (int c = 0; c < 3; c++)
            atomicAdd(&delta[((size_t)bt * E + e) * H + threadIdx.x + c * 256], acc[e][c]);
}

// ---------------------------------------------------------------------------
// K7: x[b, span+e, h] += delta[bt,e,h]  (atomic: T spans may overlap)
__global__ void k_addspan(const float* __restrict__ delta, const int* __restrict__ spans,
                          float* __restrict__ x) {
    int i = blockIdx.x * 256 + threadIdx.x;
    int h = i % H;
    int e = (i / H) % E;
    int bt = i / (H * E);
    int b = bt / T;
    atomicAdd(&x[((size_t)b * S + spans[bt] + e) * H + h], delta[i]);
}

// ---------------------------------------------------------------------------
// K8b: v2 = x@Wv+bv IN-PLACE over x. Block owns 16 rows exclusively: stages
// them transposed in LDS, then overwrites. In-place safe.
//
// R3 rewrite: R2's version was LDS-ISSUE-bound (1 LDS float per FMA; 73.7k
// ds_read_b128 wave-insts/CU ~= the whole 204 us; VALUBusy 55%, conflicts 0,
// HBM 3%). Now 256 threads x 16 rows x 3 output cols/thread: same 4x
// ds_read_b128 per h feeds 48 FMAs (12 FMA/read, 3x fewer LDS insts).
// x_s reads are wave-uniform broadcasts. LDS 48KB -> up to 3 blocks/CU.
__global__ __launch_bounds__(256, 3) void k_v2(float* __restrict__ xv,
                                               const float* __restrict__ Wv,
                                               const float* __restrict__ bv) {
    __shared__ float x_s[H][16];    // 49,152 B: [h][r]
    const int r0 = blockIdx.x * 16;
    const int t = threadIdx.x;

    // Stage transposed: thread handles row r = t&15, h-range of 48.
    {
        const int r = t & 15;
        const int h0 = (t >> 4) * 48;
        const float* xp = &xv[(size_t)(r0 + r) * H + h0];
        #pragma unroll
        for (int j = 0; j < 48; j += 4) {
            float4 v = *(const float4*)&xp[j];
            x_s[h0 + j + 0][r] = v.x;
            x_s[h0 + j + 1][r] = v.y;
            x_s[h0 + j + 2][r] = v.z;
            x_s[h0 + j + 3][r] = v.w;
        }
    }
    __syncthreads();

    float acc[3][16];
    #pragma unroll
    for (int c = 0; c < 3; c++)
        #pragma unroll
        for (int r = 0; r < 16; r++) acc[c][r] = 0.f;

    const float* wp = Wv + t;
    for (int h = 0; h < H; h += 4) {
        float w[4][3];
        #pragma unroll
        for (int u = 0; u < 4; u++) {
            const float* wr = wp + (size_t)(h + u) * H;
            w[u][0] = wr[0];
            w[u][1] = wr[256];
            w[u][2] = wr[512];
        }
        #pragma unroll
        for (int u = 0; u < 4; u++) {
            float xr[16];
            *(float4*)&xr[0]  = *(const float4*)&x_s[h + u][0];
            *(float4*)&xr[4]  = *(const float4*)&x_s[h + u][4];
            *(float4*)&xr[8]  = *(const float4*)&x_s[h + u][8];
            *(float4*)&xr[12] = *(const float4*)&x_s[h + u][12];
            #pragma unroll
            for (int c = 0; c < 3; c++)
                #pragma unroll
                for (int r = 0; r < 16; r++)
                    acc[c][r] += xr[r] * w[u][c];
        }
    }
    #pragma unroll
    for (int c = 0; c < 3; c++) {
        const float bias = bv[c * 256 + t];
        #pragma unroll
        for (int r = 0; r < 16; r++)
            xv[(size_t)(r0 + r) * H + c * 256 + t] = acc[c][r] + bias;
    }
}

// ---------------------------------------------------------------------------
extern "C" void kernel_launch(void* const* d_in, const int* in_sizes, int n_in,
                              void* d_out, int out_size, void* d_ws, size_t ws_size,
                              hipStream_t stream) {
    const float* xs    = (const float*)d_in[0];
    const float* neigh = (const float*)d_in[1];
    const float* dists = (const float*)d_in[2];
    const int*   spans = (const int*)d_in[3];
    const float* Wq = (const float*)d_in[4];
    const float* bq = (const float*)d_in[5];
    const float* Wk = (const float*)d_in[6];
    const float* bk = (const float*)d_in[7];
    const float* Wv = (const float*)d_in[8];
    const float* bv = (const float*)d_in[9];
    const float* Ww = (const float*)d_in[10];
    const float* bw = (const float*)d_in[11];
    const float* Wa = (const float*)d_in[12];
    const float* ba = (const float*)d_in[13];
    const float* wb = (const float*)d_in[14];
    const float* bb = (const float*)d_in[15];
    float* out = (float*)d_out;

    // Workspace layout (fp32), total 12,582,912 floats = 48 MiB.
    // Region A [0, 8388608): x [B,S,H] (6,291,456) | q2 | k2; v2 in-place on x.
    // Region B [8388608, 12582912): early-phase smalls (attn_p..qb0b,
    //   all dead before k_qkT) -> then Smat [B,S,S] (4,194,304).
    float* ws     = (float*)d_ws;
    float* regB   = ws + (size_t)8388608;
    float* attn_p = regB;                                 //   524,288
    float* pooled = attn_p + (size_t)B * T * N * E * L;   //   786,432
    float* delta  = pooled + (size_t)B * T * N * H;       //   196,608
    float* e_fea  = delta + (size_t)B * T * E * H;        //   196,608
    float* qb     = e_fea + (size_t)B * T * E * H;        //    32,768
    float* feas   = qb + (size_t)B * T * E * D;           //    24,576
    float* misc   = feas + (size_t)B * T * H;             //     2,048
    float* scoreb = misc + 2048;                          //     1,024
    float* qkb    = scoreb + 1024;                        //   196,608
    float* qb0b   = qkb + (size_t)B * T * E * H;          //       256
    float* x      = ws;                                   // region A
    float* q2     = ws + (size_t)B * S * H;               // alias
    float* k2     = q2 + (size_t)B * S * D;               // alias
    float* v2     = x;                                    // in-place
    float* Smat   = regB;                                 // alias (smalls dead)

    k_gather<<<B * T, 256, 0, stream>>>(xs, spans, e_fea, feas);
    k_qproj<<<B * T * E, D, 0, stream>>>(e_fea, Wq, bq, qb);
    k_qkw<<<dim3(B * T, 3), 256, 0, stream>>>(qb, Wk, bk, qkb, qb0b);
    k_sdpa<<<B * T * N, 256, 0, stream>>>(qkb, qb0b, neigh, attn_p, pooled);
    k_uv<<<3, 256, 0, stream>>>(Ww, bw, Wa, ba, wb, bb, misc);
    k_score<<<B * T * N, 256, 0, stream>>>(feas, pooled, misc, dists, scoreb);
    hipMemsetAsync(delta, 0, (size_t)B * T * E * H * sizeof(float), stream);
    k_delta<<<dim3(B * T, L / 8), 256, 0, stream>>>(attn_p, scoreb, neigh, delta);
    hipMemcpyAsync(x, xs, (size_t)B * S * H * sizeof(float), hipMemcpyDeviceToDevice, stream);
    k_addspan<<<(B * T * E * H) / 256, 256, 0, stream>>>(delta, spans, x);
    k_qk2<<<dim3(B * S / 128, 2), 256, 0, stream>>>(x, Wq, bq, Wk, bk, q2, k2);
    k_v2<<<B * S / 16, 256, 0, stream>>>(v2, Wv, bv);
    k_qkT<<<dim3(S / 128, S / 128, B), 256, 0, stream>>>(q2, k2, Smat);
    k_smax<<<B * S / 4, 256, 0, stream>>>(Smat);
    k_pv<<<dim3(S / 128, H / 128, B), 256, 0, stream>>>(Smat, v2, out);
}

// Round 4
// 903.793 us; speedup vs baseline: 1.3860x; 1.1188x over previous
//
#include <hip/hip_runtime.h>
#include <hip/hip_bf16.h>

// Problem constants (GeoUmpForPretrain) — all tensors fp32 per reference.
constexpr int B = 16, S = 512, H = 768, T = 2, N = 32, L = 64, E = 8, D = 128, A = 128;
constexpr float INV_SQRT_D = 0.08838834764831843f;  // 1/sqrt(128)

// ---------------------------------------------------------------------------
// Tiled fp32 GEMM core: C[r0:r0+128, c0:c0+128] = A @ W (+ bias)
// A: [M,K] row-major (lda); W: [K,N] row-major (ldw); C row-major (ldc).
// 256 threads, 8x8 outputs/thread, BK=32. K must be a multiple of 32.
// bias may be nullptr. One call site per kernel (one LDS allocation).
__device__ __forceinline__ void gemm128(const float* __restrict__ Ap, int lda,
                                        const float* __restrict__ W, int ldw,
                                        const float* __restrict__ bias,
                                        float* __restrict__ C, int ldc,
                                        int r0, int c0, int K) {
    __shared__ float As[32][132];   // [kk][row], row-stride 132 (16B-aligned rows)
    __shared__ float Ws[32][128];   // [kk][col]
    const int tid = threadIdx.x;
    const int tr = (tid >> 4) << 3;          // 0,8,...,120
    const int tc = (tid & 15) << 3;          // 0,8,...,120
    float acc[8][8];
    #pragma unroll
    for (int i = 0; i < 8; i++)
        #pragma unroll
        for (int j = 0; j < 8; j++) acc[i][j] = 0.f;

    const int ar = tid >> 3;                 // 0..31  (A tile row base)
    const int ak = (tid & 7) << 2;           // 0..28  (A tile col, float4)
    const int wr = tid >> 5;                 // 0..7   (W tile row base)
    const int wc = (tid & 31) << 2;          // 0..124 (W tile col, float4)

    for (int k0 = 0; k0 < K; k0 += 32) {
        float4 av[4], wv[4];
        #pragma unroll
        for (int p = 0; p < 4; p++) {
            av[p] = *(const float4*)&Ap[(size_t)(r0 + ar + 32 * p) * lda + k0 + ak];
            wv[p] = *(const float4*)&W[(size_t)(k0 + wr + 8 * p) * ldw + c0 + wc];
        }
        __syncthreads();   // previous tile's LDS reads done
        #pragma unroll
        for (int p = 0; p < 4; p++) {
            As[ak + 0][ar + 32 * p] = av[p].x;
            As[ak + 1][ar + 32 * p] = av[p].y;
            As[ak + 2][ar + 32 * p] = av[p].z;
            As[ak + 3][ar + 32 * p] = av[p].w;
            *(float4*)&Ws[wr + 8 * p][wc] = wv[p];
        }
        __syncthreads();
        #pragma unroll
        for (int kk = 0; kk < 32; kk++) {
            float a[8], b[8];
            *(float4*)&a[0] = *(const float4*)&As[kk][tr];
            *(float4*)&a[4] = *(const float4*)&As[kk][tr + 4];
            *(float4*)&b[0] = *(const float4*)&Ws[kk][tc];
            *(float4*)&b[4] = *(const float4*)&Ws[kk][tc + 4];
            #pragma unroll
            for (int i = 0; i < 8; i++)
                #pragma unroll
                for (int j = 0; j < 8; j++) acc[i][j] += a[i] * b[j];
        }
    }
    #pragma unroll
    for (int i = 0; i < 8; i++) {
        float o[8];
        #pragma unroll
        for (int j = 0; j < 8; j++)
            o[j] = acc[i][j] + (bias ? bias[c0 + tc + j] : 0.f);
        *(float4*)&C[(size_t)(r0 + tr + i) * ldc + c0 + tc] = *(float4*)&o[0];
        *(float4*)&C[(size_t)(r0 + tr + i) * ldc + c0 + tc + 4] = *(float4*)&o[4];
    }
}

// K8a: q2 = x@Wq+bq (y=0), k2 = x@Wk+bk (y=1).  grid (64, 2)
__global__ void k_qk2(const float* __restrict__ x,
                      const float* __restrict__ Wq, const float* __restrict__ bq,
                      const float* __restrict__ Wk, const float* __restrict__ bk,
                      float* __restrict__ q2, float* __restrict__ k2) {
    const float* W = blockIdx.y ? Wk : Wq;
    const float* bs = blockIdx.y ? bk : bq;
    float* C = blockIdx.y ? k2 : q2;
    gemm128(x, H, W, D, bs, C, D, blockIdx.x * 128, 0, H);
}

// K9c: out[b] = P[b] @ v2[b].  grid (4, 6, 16)
__global__ void k_pv(const float* __restrict__ P, const float* __restrict__ v2,
                     float* __restrict__ out) {
    int b = blockIdx.z;
    gemm128(P + (size_t)b * S * S, S, v2 + (size_t)b * S * H, H, nullptr,
            out + (size_t)b * S * H, H, blockIdx.x * 128, blockIdx.y * 128, S);
}

// ---------------------------------------------------------------------------
// K9a: Smat[b] = q2[b] @ k2[b]^T * INV_SQRT_D.  grid (4, 4, 16).
// Both operands staged K-major in LDS (B is transposed by staging).
__global__ void k_qkT(const float* __restrict__ q2, const float* __restrict__ k2,
                      float* __restrict__ Smat) {
    __shared__ float Qs[32][132];
    __shared__ float Ks[32][132];
    const int b = blockIdx.z;
    const int r0 = blockIdx.x * 128, c0 = blockIdx.y * 128;
    const float* Qb = q2 + (size_t)b * S * D;
    const float* Kb = k2 + (size_t)b * S * D;
    float* Sb = Smat + (size_t)b * S * S;
    const int tid = threadIdx.x;
    const int tr = (tid >> 4) << 3;
    const int tc = (tid & 15) << 3;
    const int ar = tid >> 3;             // 0..31
    const int ak = (tid & 7) << 2;       // 0..28
    float acc[8][8];
    #pragma unroll
    for (int i = 0; i < 8; i++)
        #pragma unroll
        for (int j = 0; j < 8; j++) acc[i][j] = 0.f;

    for (int k0 = 0; k0 < D; k0 += 32) {
        float4 qv[4], kv[4];
        #pragma unroll
        for (int p = 0; p < 4; p++) {
            qv[p] = *(const float4*)&Qb[(size_t)(r0 + ar + 32 * p) * D + k0 + ak];
            kv[p] = *(const float4*)&Kb[(size_t)(c0 + ar + 32 * p) * D + k0 + ak];
        }
        __syncthreads();
        #pragma unroll
        for (int p = 0; p < 4; p++) {
            Qs[ak + 0][ar + 32 * p] = qv[p].x;
            Qs[ak + 1][ar + 32 * p] = qv[p].y;
            Qs[ak + 2][ar + 32 * p] = qv[p].z;
            Qs[ak + 3][ar + 32 * p] = qv[p].w;
            Ks[ak + 0][ar + 32 * p] = kv[p].x;
            Ks[ak + 1][ar + 32 * p] = kv[p].y;
            Ks[ak + 2][ar + 32 * p] = kv[p].z;
            Ks[ak + 3][ar + 32 * p] = kv[p].w;
        }
        __syncthreads();
        #pragma unroll
        for (int kk = 0; kk < 32; kk++) {
            float a[8], bb_[8];
            *(float4*)&a[0] = *(const float4*)&Qs[kk][tr];
            *(float4*)&a[4] = *(const float4*)&Qs[kk][tr + 4];
            *(float4*)&bb_[0] = *(const float4*)&Ks[kk][tc];
            *(float4*)&bb_[4] = *(const float4*)&Ks[kk][tc + 4];
            #pragma unroll
            for (int i = 0; i < 8; i++)
                #pragma unroll
                for (int j = 0; j < 8; j++) acc[i][j] += a[i] * bb_[j];
        }
    }
    #pragma unroll
    for (int i = 0; i < 8; i++) {
        float o[8];
        #pragma unroll
        for (int j = 0; j < 8; j++) o[j] = acc[i][j] * INV_SQRT_D;
        *(float4*)&Sb[(size_t)(r0 + tr + i) * S + c0 + tc] = *(float4*)&o[0];
        *(float4*)&Sb[(size_t)(r0 + tr + i) * S + c0 + tc + 4] = *(float4*)&o[4];
    }
}

// K9b: in-place row softmax on Smat. One wave per row; 4 rows/block.
__global__ void k_smax(float* __restrict__ Smat) {
    int row = blockIdx.x * 4 + (threadIdx.x >> 6);
    int lane = threadIdx.x & 63;
    float* p = Smat + (size_t)row * S;
    float4 v0 = *(const float4*)&p[lane * 4];
    float4 v1 = *(const float4*)&p[256 + lane * 4];
    float m = fmaxf(fmaxf(fmaxf(v0.x, v0.y), fmaxf(v0.z, v0.w)),
                    fmaxf(fmaxf(v1.x, v1.y), fmaxf(v1.z, v1.w)));
    #pragma unroll
    for (int off = 32; off; off >>= 1) m = fmaxf(m, __shfl_xor(m, off, 64));
    v0.x = expf(v0.x - m); v0.y = expf(v0.y - m);
    v0.z = expf(v0.z - m); v0.w = expf(v0.w - m);
    v1.x = expf(v1.x - m); v1.y = expf(v1.y - m);
    v1.z = expf(v1.z - m); v1.w = expf(v1.w - m);
    float s = v0.x + v0.y + v0.z + v0.w + v1.x + v1.y + v1.z + v1.w;
    #pragma unroll
    for (int off = 32; off; off >>= 1) s += __shfl_xor(s, off, 64);
    float inv = 1.0f / s;
    v0.x *= inv; v0.y *= inv; v0.z *= inv; v0.w *= inv;
    v1.x *= inv; v1.y *= inv; v1.z *= inv; v1.w *= inv;
    *(float4*)&p[lane * 4] = v0;
    *(float4*)&p[256 + lane * 4] = v1;
}

// ---------------------------------------------------------------------------
// K1: gather entity spans -> e_fea [B,T,E,H], feas = mean over E [B,T,H]
__global__ void k_gather(const float* __restrict__ xs,
                         const int* __restrict__ spans,
                         float* __restrict__ e_fea, float* __restrict__ feas) {
    int bt = blockIdx.x;
    int b = bt / T;
    int span = spans[bt];
    for (int h = threadIdx.x; h < H; h += 256) {
        float acc = 0.f;
        for (int e = 0; e < E; e++) {
            float v = xs[((size_t)b * S + span + e) * H + h];
            e_fea[((size_t)bt * E + e) * H + h] = v;
            acc += v;
        }
        feas[(size_t)bt * H + h] = acc * (1.0f / E);
    }
}

// ---------------------------------------------------------------------------
// K2: q = e_fea @ Wq + bq   [B*T*E, D]  (tiny: 256 rows)
__global__ void k_qproj(const float* __restrict__ e_fea,
                        const float* __restrict__ Wq,
                        const float* __restrict__ bq,
                        float* __restrict__ q) {
    int row = blockIdx.x;
    int d = threadIdx.x;
    const float* er = e_fea + (size_t)row * H;
    float acc = bq[d];
    #pragma unroll 4
    for (int h = 0; h < H; h++) acc += er[h] * Wq[(size_t)h * D + d];
    q[(size_t)row * D + d] = acc;
}

// ---------------------------------------------------------------------------
// K2b: qk[bt,e,h] = sum_d q[bt,e,d]*Wk[h,d];  qb0[bt,e] = q[bt,e,:].bk
// R4: blockIdx.y==0 additionally computes feasv[bt] = feas[bt,:].misc[0:H]
// (the feas-side of the score dot), so k_score can be deleted entirely.
__global__ void k_qkw(const float* __restrict__ q, const float* __restrict__ Wk,
                      const float* __restrict__ bk,
                      const float* __restrict__ feas, const float* __restrict__ misc,
                      float* __restrict__ qkb, float* __restrict__ qb0,
                      float* __restrict__ feasv) {
    __shared__ float q_s[E * D];   // 4 KB
    __shared__ float redf[4];
    const int bt = blockIdx.x;
    const float* qp = q + (size_t)bt * E * D;
    for (int i = threadIdx.x; i < E * D; i += 256) q_s[i] = qp[i];
    __syncthreads();
    const int h = blockIdx.y * 256 + threadIdx.x;
    float acc[E];
    #pragma unroll
    for (int e = 0; e < E; e++) acc[e] = 0.f;
    const float* wrow = Wk + (size_t)h * D;
    for (int d = 0; d < D; d += 4) {
        float4 wv = *(const float4*)&wrow[d];
        #pragma unroll
        for (int e = 0; e < E; e++) {
            float4 qv = *(const float4*)&q_s[e * D + d];
            acc[e] += qv.x * wv.x + qv.y * wv.y + qv.z * wv.z + qv.w * wv.w;
        }
    }
    #pragma unroll
    for (int e = 0; e < E; e++)
        qkb[((size_t)bt * E + e) * H + h] = acc[e];
    if (blockIdx.y == 0) {
        if (threadIdx.x < E) {
            int e = threadIdx.x;
            float s = 0.f;
            for (int d = 0; d < D; d++) s += q_s[e * D + d] * bk[d];
            qb0[bt * E + e] = s;
        }
        // feasv[bt] = feas . misc[0:H]
        float part = 0.f;
        for (int hh = threadIdx.x; hh < H; hh += 256)
            part += feas[(size_t)bt * H + hh] * misc[hh];
        #pragma unroll
        for (int off = 32; off > 0; off >>= 1) part += __shfl_down(part, off, 64);
        if ((threadIdx.x & 63) == 0) redf[threadIdx.x >> 6] = part;
        __syncthreads();
        if (threadIdx.x == 0)
            feasv[bt] = redf[0] + redf[1] + redf[2] + redf[3];
    }
}

// ---------------------------------------------------------------------------
// K4 (R4 rewrite): fuses the old k_sdpa + pooled + k_score.
// Per (b,t,n): logits[e,l] = (qk[bt,e,:].neigh[btn,l,:] + qb0[bt,e])*isqrtD;
// softmax over l -> attn_p. During the SAME chunk loop accumulate
// nu[l] = neigh[l,:].u (u = misc[H:2H]); then
// score[btn] = sigmoid(leaky(feasv[bt] + sum_l abar[l]*nu[l] + c0) + dist*wb + bb).
// This deletes the pooled second pass (was ~half the kernel) and k_score.
// Chunk loads are float4 + 1-chunk register prefetch (T14): HBM latency hides
// under compute+barriers. LDS 47.5 KB -> 3 blocks/CU.
__global__ __launch_bounds__(256, 3) void k_sdpa(
        const float* __restrict__ qkb, const float* __restrict__ qb0,
        const float* __restrict__ neigh, const float* __restrict__ misc,
        const float* __restrict__ feasv, const float* __restrict__ dists,
        float* __restrict__ attn_p, float* __restrict__ score) {
    __shared__ float qk_s[E * H];      // 24,576 B
    __shared__ float u_s[64 * 69];     // 17,664 B: chunk; later red[2048]+nured[256]
    __shared__ float uvec[H];          //  3,072 B: misc[H:2H]
    __shared__ float attn_s[E * L];    //  2,048 B
    __shared__ float qb0_s[E];
    const int btn = blockIdx.x;
    const int bt = btn >> 5;           // / N
    const float* qkp = qkb + (size_t)bt * E * H;
    const float* nrow = neigh + (size_t)btn * L * H;
    const int tid = threadIdx.x;
    const int l = tid & 63;            // lane -> neighbor token
    const int g = tid >> 6;            // wave -> 16-wide h-slice
    const int hb = g * 16;

    for (int i = tid; i < E * H / 4; i += 256)
        *(float4*)&qk_s[i * 4] = *(const float4*)&qkp[i * 4];
    for (int i = tid; i < H / 4; i += 256)
        *(float4*)&uvec[i * 4] = *(const float4*)&misc[H + i * 4];
    if (tid < E) qb0_s[tid] = qb0[bt * E + tid];

    float acc[E];
    #pragma unroll
    for (int e = 0; e < E; e++) acc[e] = 0.f;
    float nu = 0.f;

    // prefetch chunk 0 (coalesced float4: 64 lanes cover 4 rows x 256B)
    const int pll = tid >> 4;          // 0..15 (row base within 16-row group)
    const int ph4 = (tid & 15) * 4;    // 0..60
    float4 pr[4];
    #pragma unroll
    for (int j = 0; j < 4; j++)
        pr[j] = *(const float4*)&nrow[(size_t)(j * 16 + pll) * H + ph4];

    for (int c = 0; c < H / 64; c++) {       // 12 chunks of 64 h
        const int h0 = c * 64;
        __syncthreads();                     // u_s free (prev compute done)
        #pragma unroll
        for (int j = 0; j < 4; j++) {
            const int base = (j * 16 + pll) * 69 + ph4;
            u_s[base + 0] = pr[j].x;
            u_s[base + 1] = pr[j].y;
            u_s[base + 2] = pr[j].z;
            u_s[base + 3] = pr[j].w;
        }
        if (c + 1 < H / 64) {                // issue next chunk's loads now;
            #pragma unroll                   // they complete under compute(c)
            for (int j = 0; j < 4; j++)
                pr[j] = *(const float4*)&nrow[(size_t)(j * 16 + pll) * H + h0 + 64 + ph4];
        }
        __syncthreads();                     // u_s ready (covers qk_s/uvec @c=0)
        #pragma unroll
        for (int h = 0; h < 16; h += 4) {
            float n0 = u_s[l * 69 + hb + h + 0];
            float n1 = u_s[l * 69 + hb + h + 1];
            float n2 = u_s[l * 69 + hb + h + 2];
            float n3 = u_s[l * 69 + hb + h + 3];
            #pragma unroll
            for (int e = 0; e < E; e++) {
                float4 qv = *(const float4*)&qk_s[e * H + h0 + hb + h];
                acc[e] += qv.x * n0 + qv.y * n1 + qv.z * n2 + qv.w * n3;
            }
            float4 uq = *(const float4*)&uvec[h0 + hb + h];
            nu += n0 * uq.x + n1 * uq.y + n2 * uq.z + n3 * uq.w;
        }
    }
    __syncthreads();                         // last compute done; u_s -> red
    float* red = u_s;                        // red[g*512 + l*8 + e]
    float* nured = u_s + 2048;               // nured[g*64 + l]
    *(float4*)&red[g * 512 + l * 8 + 0] = make_float4(acc[0], acc[1], acc[2], acc[3]);
    *(float4*)&red[g * 512 + l * 8 + 4] = make_float4(acc[4], acc[5], acc[6], acc[7]);
    nured[g * 64 + l] = nu;
    __syncthreads();
    for (int p = tid; p < E * L; p += 256) {
        int e = p >> 6, ll = p & 63;
        float s = red[ll * 8 + e] + red[512 + ll * 8 + e] +
                  red[1024 + ll * 8 + e] + red[1536 + ll * 8 + e];
        attn_s[e * L + ll] = (s + qb0_s[e]) * INV_SQRT_D;
    }
    __syncthreads();

    if (tid < E) {
        int e = tid;
        float m = -1e30f;
        for (int ll = 0; ll < L; ll++) m = fmaxf(m, attn_s[e * L + ll]);
        float ssum = 0.f;
        for (int ll = 0; ll < L; ll++) {
            float ex = expf(attn_s[e * L + ll] - m);
            attn_s[e * L + ll] = ex;
            ssum += ex;
        }
        float inv = 1.0f / ssum;
        for (int ll = 0; ll < L; ll++) attn_s[e * L + ll] *= inv;
    }
    __syncthreads();

    for (int i = tid; i < E * L; i += 256)
        attn_p[(size_t)btn * E * L + i] = attn_s[i];

    if (tid < 64) {                          // score: one wave
        float a = 0.f;
        #pragma unroll
        for (int e = 0; e < E; e++) a += attn_s[e * L + tid];
        a *= (1.0f / E);
        float nl = nured[tid] + nured[64 + tid] + nured[128 + tid] + nured[192 + tid];
        float part = a * nl;
        #pragma unroll
        for (int off = 32; off > 0; off >>= 1) part += __shfl_xor(part, off, 64);
        if (tid == 0) {
            float tot = feasv[bt] + part + misc[2 * H];
            float lk = tot > 0.f ? tot : 0.01f * tot;
            float xatt = lk + dists[btn] * misc[2 * H + 1] + misc[2 * H + 2];
            score[btn] = 1.0f / (1.0f + expf(-xatt));
        }
    }
}

// ---------------------------------------------------------------------------
// K5a: fold Ww/Wa/bw/ba/wb/bb into misc
__global__ void k_uv(const float* __restrict__ Ww, const float* __restrict__ bw,
                     const float* __restrict__ Wa, const float* __restrict__ ba,
                     const float* __restrict__ wb, const float* __restrict__ bb,
                     float* __restrict__ misc) {
    int h = blockIdx.x * blockDim.x + threadIdx.x;
    if (h < H) {
        float lo = 0.f, hi = 0.f;
        for (int a = 0; a < A; a++) {
            float w = Ww[(size_t)h * A + a];
            lo += w * Wa[a];
            hi += w * Wa[A + a];
        }
        misc[h] = lo;
        misc[H + h] = hi;
    }
    if (blockIdx.x == 0 && threadIdx.x == 0) {
        float c = ba[0];
        for (int a = 0; a < A; a++) c += bw[a] * (Wa[a] + Wa[A + a]);
        misc[2 * H] = c;
        misc[2 * H + 1] = wb[0];
        misc[2 * H + 2] = bb[0];
    }
}

// ---------------------------------------------------------------------------
// K6: delta[bt,e,h] += sum_{n, l-chunk} score_n * attn_p[n,e,l] * neigh[l,h]
__global__ void k_delta(const float* __restrict__ attn_p, const float* __restrict__ score,
                        const float* __restrict__ neigh, float* __restrict__ delta) {
    __shared__ float w_s[E * 8];
    int bt = blockIdx.x, l0 = blockIdx.y * 8;
    float acc[E][3];
    #pragma unroll
    for (int e = 0; e < E; e++)
        #pragma unroll
        for (int c = 0; c < 3; c++) acc[e][c] = 0.f;
    for (int n = 0; n < N; n++) {
        int btn = bt * N + n;
        if (threadIdx.x < E * 8) {
            int e = threadIdx.x >> 3, lp = threadIdx.x & 7;
            w_s[threadIdx.x] = score[btn] * attn_p[((size_t)btn * E + e) * L + l0 + lp];
        }
        __syncthreads();
        const float* nrow = neigh + ((size_t)btn * L + l0) * H;
        for (int lp = 0; lp < 8; lp++) {
            float nv[3];
            #pragma unroll
            for (int c = 0; c < 3; c++) nv[c] = nrow[(size_t)lp * H + threadIdx.x + c * 256];
            #pragma unroll
            for (int e = 0; e < E; e++) {
                float w = w_s[e * 8 + lp];
                #pragma unroll
                for (int c = 0; c < 3; c++) acc[e][c] += w * nv[c];
            }
        }
        __syncthreads();
    }
    #pragma unroll
    for (int e = 0; e < E; e++)
        #pragma unroll
        for (int c = 0; c < 3; c++)
            atomicAdd(&delta[((size_t)bt * E + e) * H + threadIdx.x + c * 256], acc[e][c]);
}

// ---------------------------------------------------------------------------
// K7: x[b, span+e, h] += delta[bt,e,h]  (atomic: T spans may overlap)
__global__ void k_addspan(const float* __restrict__ delta, const int* __restrict__ spans,
                          float* __restrict__ x) {
    int i = blockIdx.x * 256 + threadIdx.x;
    int h = i % H;
    int e = (i / H) % E;
    int bt = i / (H * E);
    int b = bt / T;
    atomicAdd(&x[((size_t)b * S + spans[bt] + e) * H + h], delta[i]);
}

// ---------------------------------------------------------------------------
// K8b: v2 = x@Wv+bv IN-PLACE over x. Block owns 16 rows exclusively: stages
// them transposed in LDS, then overwrites. In-place safe.
// R3: 256 threads x 16 rows x 3 output cols/thread; 4x ds_read_b128 per h
// feeds 48 FMAs (12 FMA/read). LDS 48KB -> 3 blocks/CU.
__global__ __launch_bounds__(256, 3) void k_v2(float* __restrict__ xv,
                                               const float* __restrict__ Wv,
                                               const float* __restrict__ bv) {
    __shared__ float x_s[H][16];    // 49,152 B: [h][r]
    const int r0 = blockIdx.x * 16;
    const int t = threadIdx.x;

    // Stage transposed: thread handles row r = t&15, h-range of 48.
    {
        const int r = t & 15;
        const int h0 = (t >> 4) * 48;
        const float* xp = &xv[(size_t)(r0 + r) * H + h0];
        #pragma unroll
        for (int j = 0; j < 48; j += 4) {
            float4 v = *(const float4*)&xp[j];
            x_s[h0 + j + 0][r] = v.x;
            x_s[h0 + j + 1][r] = v.y;
            x_s[h0 + j + 2][r] = v.z;
            x_s[h0 + j + 3][r] = v.w;
        }
    }
    __syncthreads();

    float acc[3][16];
    #pragma unroll
    for (int c = 0; c < 3; c++)
        #pragma unroll
        for (int r = 0; r < 16; r++) acc[c][r] = 0.f;

    const float* wp = Wv + t;
    for (int h = 0; h < H; h += 4) {
        float w[4][3];
        #pragma unroll
        for (int u = 0; u < 4; u++) {
            const float* wr = wp + (size_t)(h + u) * H;
            w[u][0] = wr[0];
            w[u][1] = wr[256];
            w[u][2] = wr[512];
        }
        #pragma unroll
        for (int u = 0; u < 4; u++) {
            float xr[16];
            *(float4*)&xr[0]  = *(const float4*)&x_s[h + u][0];
            *(float4*)&xr[4]  = *(const float4*)&x_s[h + u][4];
            *(float4*)&xr[8]  = *(const float4*)&x_s[h + u][8];
            *(float4*)&xr[12] = *(const float4*)&x_s[h + u][12];
            #pragma unroll
            for (int c = 0; c < 3; c++)
                #pragma unroll
                for (int r = 0; r < 16; r++)
                    acc[c][r] += xr[r] * w[u][c];
        }
    }
    #pragma unroll
    for (int c = 0; c < 3; c++) {
        const float bias = bv[c * 256 + t];
        #pragma unroll
        for (int r = 0; r < 16; r++)
            xv[(size_t)(r0 + r) * H + c * 256 + t] = acc[c][r] + bias;
    }
}

// ---------------------------------------------------------------------------
extern "C" void kernel_launch(void* const* d_in, const int* in_sizes, int n_in,
                              void* d_out, int out_size, void* d_ws, size_t ws_size,
                              hipStream_t stream) {
    const float* xs    = (const float*)d_in[0];
    const float* neigh = (const float*)d_in[1];
    const float* dists = (const float*)d_in[2];
    const int*   spans = (const int*)d_in[3];
    const float* Wq = (const float*)d_in[4];
    const float* bq = (const float*)d_in[5];
    const float* Wk = (const float*)d_in[6];
    const float* bk = (const float*)d_in[7];
    const float* Wv = (const float*)d_in[8];
    const float* bv = (const float*)d_in[9];
    const float* Ww = (const float*)d_in[10];
    const float* bw = (const float*)d_in[11];
    const float* Wa = (const float*)d_in[12];
    const float* ba = (const float*)d_in[13];
    const float* wb = (const float*)d_in[14];
    const float* bb = (const float*)d_in[15];
    float* out = (float*)d_out;

    // Workspace layout (fp32), total 12,582,912 floats = 48 MiB.
    // Region A [0, 8388608): x [B,S,H] (6,291,456) | q2 | k2; v2 in-place on x.
    // Region B [8388608, 12582912): early-phase smalls (all dead before k_qkT)
    //   -> then Smat [B,S,S] (4,194,304).
    float* ws     = (float*)d_ws;
    float* regB   = ws + (size_t)8388608;
    float* attn_p = regB;                                 //   524,288
    float* delta  = attn_p + (size_t)B * T * N * E * L;   //   196,608
    float* e_fea  = delta + (size_t)B * T * E * H;        //   196,608
    float* qb     = e_fea + (size_t)B * T * E * H;        //    32,768
    float* feas   = qb + (size_t)B * T * E * D;           //    24,576
    float* misc   = feas + (size_t)B * T * H;             //     2,048
    float* scoreb = misc + 2048;                          //     1,024
    float* qkb    = scoreb + 1024;                        //   196,608
    float* qb0b   = qkb + (size_t)B * T * E * H;          //       256
    float* feasvb = qb0b + 256;                           //        32
    float* x      = ws;                                   // region A
    float* q2     = ws + (size_t)B * S * H;               // alias
    float* k2     = q2 + (size_t)B * S * D;               // alias
    float* v2     = x;                                    // in-place
    float* Smat   = regB;                                 // alias (smalls dead)

    k_gather<<<B * T, 256, 0, stream>>>(xs, spans, e_fea, feas);
    k_uv<<<3, 256, 0, stream>>>(Ww, bw, Wa, ba, wb, bb, misc);
    k_qproj<<<B * T * E, D, 0, stream>>>(e_fea, Wq, bq, qb);
    k_qkw<<<dim3(B * T, 3), 256, 0, stream>>>(qb, Wk, bk, feas, misc, qkb, qb0b, feasvb);
    k_sdpa<<<B * T * N, 256, 0, stream>>>(qkb, qb0b, neigh, misc, feasvb, dists,
                                          attn_p, scoreb);
    hipMemsetAsync(delta, 0, (size_t)B * T * E * H * sizeof(float), stream);
    k_delta<<<dim3(B * T, L / 8), 256, 0, stream>>>(attn_p, scoreb, neigh, delta);
    hipMemcpyAsync(x, xs, (size_t)B * S * H * sizeof(float), hipMemcpyDeviceToDevice, stream);
    k_addspan<<<(B * T * E * H) / 256, 256, 0, stream>>>(delta, spans, x);
    k_qk2<<<dim3(B * S / 128, 2), 256, 0, stream>>>(x, Wq, bq, Wk, bk, q2, k2);
    k_v2<<<B * S / 16, 256, 0, stream>>>(v2, Wv, bv);
    k_qkT<<<dim3(S / 128, S / 128, B), 256, 0, stream>>>(q2, k2, Smat);
    k_smax<<<B * S / 4, 256, 0, stream>>>(Smat);
    k_pv<<<dim3(S / 128, H / 128, B), 256, 0, stream>>>(Smat, v2, out);
}